// Round 5
// baseline (808.906 us; speedup 1.0000x reference)
//
#include <hip/hip_runtime.h>
#include <math.h>

// ---------------------------------------------------------------------------
// FrameTransformer — GEMM v3: BM x BN tile templated (64/128), BK=64,
// kc-major LDS (0 bank conflicts, verified R4), XCD swizzle (verified R4,
// FETCH 75->33 MB). Tile choice targets >=3-4 blocks/CU per GEMM, since
// R2-R4 shows throughput ~ linear in resident blocks (1/CU=130TF, 2/CU=177TF).
// ---------------------------------------------------------------------------

typedef unsigned short u16;
typedef __attribute__((ext_vector_type(4))) float floatx4;
typedef __attribute__((ext_vector_type(8))) short short8;

#define NB 4
static const long long M1 = 1024LL * 1024LL;

__device__ __forceinline__ float bf2f(u16 h) {
    union { unsigned int u; float f; } v;
    v.u = ((unsigned int)h) << 16;
    return v.f;
}
__device__ __forceinline__ u16 f2bf(float x) {
    union { float f; unsigned int u; } v;
    v.f = x;
    unsigned int r = (v.u + 0x7FFFu + ((v.u >> 16) & 1u)) >> 16;
    return (u16)r;
}

__device__ __forceinline__ void async_cp16(const u16* g, u16* lds) {
    __builtin_amdgcn_global_load_lds(
        (const __attribute__((address_space(1))) unsigned int*)g,
        (__attribute__((address_space(3))) unsigned int*)lds, 16, 0, 0);
}

__device__ __forceinline__ float block_sum(float v) {
    __shared__ float sd[4];
    #pragma unroll
    for (int off = 32; off; off >>= 1) v += __shfl_down(v, off, 64);
    int lane = threadIdx.x & 63, wid = threadIdx.x >> 6;
    __syncthreads();
    if (lane == 0) sd[wid] = v;
    __syncthreads();
    return sd[0] + sd[1] + sd[2] + sd[3];
}
__device__ __forceinline__ float block_max(float v) {
    __shared__ float sd[4];
    #pragma unroll
    for (int off = 32; off; off >>= 1) v = fmaxf(v, __shfl_down(v, off, 64));
    int lane = threadIdx.x & 63, wid = threadIdx.x >> 6;
    __syncthreads();
    if (lane == 0) sd[wid] = v;
    __syncthreads();
    return fmaxf(fmaxf(sd[0], sd[1]), fmaxf(sd[2], sd[3]));
}

// ---------------------------------------------------------------------------
// bf16 NT GEMM v3: C[M,N] (op)= act( scale*(A·B^T + bias) )
// A [M,K] bf16, B [N,K] bf16, row-major. Tile BM x BN, BK=64, 4 waves in
// 2x2 -> wave tile (BM/2) x (BN/2). LDS kc-major: As[kc][row][8elem] so all
// ds_read_b128 are conflict-free. XCD swizzle: id&7 = m-stripe residue.
// Requires: M%BM==0, N%BN==0, K%64==0, (M/BM)%8==0.
// ---------------------------------------------------------------------------
template<int BM, int BN, int ACT, bool ACCUM, bool OBF>
__global__ __launch_bounds__(256)
void gemm_bf(const u16* __restrict__ A, const u16* __restrict__ B,
             void* __restrict__ Cv, int K, int lda, int ldb, int ldc,
             long long sAz, long long sBz, long long sCz,
             const float* __restrict__ bias, float scale)
{
    constexpr int MI = BM / 32;        // a-frags per wave
    constexpr int NJ = BN / 32;        // b-frags per wave

    A += (long long)blockIdx.z * sAz;
    B += (long long)blockIdx.z * sBz;
    const long long zc = (long long)blockIdx.z * sCz;

    __shared__ u16 As[8 * BM * 8];     // kc-major
    __shared__ u16 Bs[8 * BN * 8];

    // XCD-aware swizzle (round-robin block->XCD by linear id)
    const int id = blockIdx.x + gridDim.x * blockIdx.y;
    const int bx = (id >> 3) % gridDim.x;
    const int by = (id & 7) + 8 * ((id >> 3) / gridDim.x);
    const int m0 = by * BM;
    const int n0 = bx * BN;

    const int tid  = threadIdx.x;
    const int lane = tid & 63;
    const int w    = tid >> 6;
    const int wm   = (w >> 1) * (BM / 2);
    const int wn   = (w & 1) * (BN / 2);

    floatx4 acc[MI][NJ];
    #pragma unroll
    for (int i = 0; i < MI; i++)
        #pragma unroll
        for (int j = 0; j < NJ; j++)
            acc[i][j] = floatx4{0.f, 0.f, 0.f, 0.f};

    for (int k0 = 0; k0 < K; k0 += 64) {
        // stage A: BM/32 insts per wave (rowgroups x kc pairs)
        #pragma unroll
        for (int r = 0; r < BM / 32; r++) {
            const int kc = 2 * w + (r & 1);
            const int rg = r >> 1;
            async_cp16(A + (long long)(m0 + rg * 64 + lane) * lda + k0 + kc * 8,
                       &As[(kc * BM + rg * 64) * 8]);
        }
        #pragma unroll
        for (int r = 0; r < BN / 32; r++) {
            const int kc = 2 * w + (r & 1);
            const int rg = r >> 1;
            async_cp16(B + (long long)(n0 + rg * 64 + lane) * ldb + k0 + kc * 8,
                       &Bs[(kc * BN + rg * 64) * 8]);
        }
        __syncthreads();

        #pragma unroll
        for (int s = 0; s < 2; s++) {
            short8 a[MI], b[NJ];
            const int fr = lane & 15;
            const int kc = s * 4 + (lane >> 4);
            #pragma unroll
            for (int i = 0; i < MI; i++)
                a[i] = *(const short8*)&As[(kc * BM + wm + i * 16 + fr) * 8];
            #pragma unroll
            for (int j = 0; j < NJ; j++)
                b[j] = *(const short8*)&Bs[(kc * BN + wn + j * 16 + fr) * 8];
            #pragma unroll
            for (int i = 0; i < MI; i++)
                #pragma unroll
                for (int j = 0; j < NJ; j++)
                    acc[i][j] = __builtin_amdgcn_mfma_f32_16x16x32_bf16(
                        a[i], b[j], acc[i][j], 0, 0, 0);
        }
        __syncthreads();
    }

    float* Cf = (float*)Cv;
    u16*  Cb  = (u16*)Cv;
    const int cn    = n0 + wn + (lane & 15);
    const int rbase = m0 + wm + (lane >> 4) * 4;
    float bj[NJ];
    #pragma unroll
    for (int j = 0; j < NJ; j++) bj[j] = bias ? bias[cn + j * 16] : 0.f;

    #pragma unroll
    for (int i = 0; i < MI; i++) {
        #pragma unroll
        for (int r = 0; r < 4; r++) {
            const int m = rbase + i * 16 + r;
            #pragma unroll
            for (int j = 0; j < NJ; j++) {
                const int n = cn + j * 16;
                float v = (acc[i][j][r] + bj[j]) * scale;
                if (ACT == 1) v = fmaxf(v, 0.f);
                else if (ACT == 2) { v = fmaxf(v, 0.f); v = v * v; }
                const long long ci = zc + (long long)m * ldc + n;
                if (OBF)        Cb[ci] = f2bf(v);
                else if (ACCUM) Cf[ci] += v;
                else            Cf[ci] = v;
            }
        }
    }
}

// ---------------------------------------------------------------------------
__global__ __launch_bounds__(256)
void ln_bf_k(const float* __restrict__ in, u16* __restrict__ out,
             const float* __restrict__ g, const float* __restrict__ b)
{
    long long row = blockIdx.x;
    const float4* ip = (const float4*)(in + (row << 10));
    int tid = threadIdx.x;
    float4 v = ip[tid];
    float s = v.x + v.y + v.z + v.w;
    s = block_sum(s);
    float mean = s * (1.f / 1024.f);
    float dx = v.x - mean, dy = v.y - mean, dz = v.z - mean, dw = v.w - mean;
    float s2 = dx * dx + dy * dy + dz * dz + dw * dw;
    s2 = block_sum(s2);
    float inv = rsqrtf(s2 * (1.f / 1024.f) + 1e-5f);
    float4 gg = ((const float4*)g)[tid];
    float4 bb = ((const float4*)b)[tid];
    ushort4 o;
    o.x = f2bf(dx * inv * gg.x + bb.x);
    o.y = f2bf(dy * inv * gg.y + bb.y);
    o.z = f2bf(dz * inv * gg.z + bb.z);
    o.w = f2bf(dw * inv * gg.w + bb.w);
    ((ushort4*)(out + (row << 10)))[tid] = o;
}

__global__ __launch_bounds__(256)
void softmax_bf_k(u16* __restrict__ S)
{
    long long row = blockIdx.x;
    u16* p = S + (row << 10);
    int tid = threadIdx.x;
    ushort4 u = ((ushort4*)p)[tid];
    float x0 = bf2f(u.x), x1 = bf2f(u.y), x2 = bf2f(u.z), x3 = bf2f(u.w);
    float m = fmaxf(fmaxf(x0, x1), fmaxf(x2, x3));
    m = block_max(m);
    x0 = expf(x0 - m); x1 = expf(x1 - m); x2 = expf(x2 - m); x3 = expf(x3 - m);
    float s = x0 + x1 + x2 + x3;
    s = block_sum(s);
    float r = 1.f / s;
    u.x = f2bf(x0 * r); u.y = f2bf(x1 * r); u.z = f2bf(x2 * r); u.w = f2bf(x3 * r);
    ((ushort4*)p)[tid] = u;
}

__global__ __launch_bounds__(256)
void inproj_k(const float* __restrict__ src, const float* __restrict__ inw,
              float* __restrict__ X)
{
    __shared__ float tile[32][33];
    int b = blockIdx.z;
    int f0 = blockIdx.y * 32, t0 = blockIdx.x * 32;
    float w0 = inw[0], w1 = inw[1];
    for (int r = threadIdx.y; r < 32; r += 8) {
        int f = f0 + r, t = t0 + threadIdx.x;
        float s0 = src[(((long long)b * 2 + 0) * 1025 + f) * 1024 + t];
        float s1 = src[(((long long)b * 2 + 1) * 1025 + f) * 1024 + t];
        tile[r][threadIdx.x] = w0 * s0 + w1 * s1;
    }
    __syncthreads();
    for (int r = threadIdx.y; r < 32; r += 8)
        X[((long long)b * 1024 + t0 + r) * 1024 + f0 + threadIdx.x] = tile[threadIdx.x][r];
}

__global__ __launch_bounds__(256)
void glu_k(const float* __restrict__ G, float* __restrict__ X)
{
    int idx = blockIdx.x * 256 + threadIdx.x;   // 1M float4 groups
    int f4 = idx & 255;
    long long row = idx >> 8;
    float4 a = *(const float4*)(G + row * 2048 + f4 * 4);
    float4 s = *(const float4*)(G + row * 2048 + 1024 + f4 * 4);
    float4* xp = (float4*)(X + row * 1024 + f4 * 4);
    float4 x = *xp;
    x.x += a.x / (1.f + expf(-s.x));
    x.y += a.y / (1.f + expf(-s.y));
    x.z += a.z / (1.f + expf(-s.z));
    x.w += a.w / (1.f + expf(-s.w));
    *xp = x;
}

// dconv along f (contiguous), channels=t, k=11 pad 5, transposed out[b][f][t].
__global__ __launch_bounds__(256)
void dconvF_t_k(const u16* __restrict__ in, u16* __restrict__ out,
                const float* __restrict__ w)
{
    __shared__ float itile[32][44];
    __shared__ float otile[32][33];
    int b = blockIdx.z, t0 = blockIdx.y * 32, f0 = blockIdx.x * 32;
    int tx = threadIdx.x & 31, ty = threadIdx.x >> 5;
    for (int r = ty; r < 32; r += 8)
        for (int c = tx; c < 42; c += 32) {
            int f = f0 - 5 + c;
            itile[r][c] = (f >= 0 && f < 1024)
                ? bf2f(in[((long long)(b * 1024 + t0 + r)) * 1024 + f]) : 0.f;
        }
    __syncthreads();
    for (int r = ty; r < 32; r += 8) {
        const float* wr = w + (t0 + r) * 11;
        float acc = 0.f;
        #pragma unroll
        for (int k = 0; k < 11; k++) acc += itile[r][tx + k] * wr[k];
        otile[tx][r] = acc;
    }
    __syncthreads();
    for (int r = ty; r < 32; r += 8)
        out[((long long)(b * 1024 + f0 + r)) * 1024 + t0 + tx] = f2bf(otile[r][tx]);
}

// dconv along t (strided), channels=f, k=7 pad 3, bf16 (B,T,F)->(B,T,F).
__global__ __launch_bounds__(256)
void dconvT_bf_k(const u16* __restrict__ in, u16* __restrict__ out,
                 const float* __restrict__ w)
{
    int idx = blockIdx.x * 256 + threadIdx.x;
    int f = idx & 1023;
    int bt = idx >> 10;
    int t = bt & 1023;
    int b = bt >> 10;
    const float* wr = w + f * 7;
    float acc = 0.f;
    #pragma unroll
    for (int k = 0; k < 7; k++) {
        int tt = t + k - 3;
        if (tt >= 0 && tt < 1024)
            acc += bf2f(in[(((long long)b << 10) + tt) * 1024 + f]) * wr[k];
    }
    out[idx] = f2bf(acc);
}

// V path: dconv along t on T3 v-plane (stride 3072, offset 2048) + bias,
// transposed out Vt[b][f][t].
__global__ __launch_bounds__(256)
void vconv_t_k(const u16* __restrict__ T3, u16* __restrict__ out,
               const float* __restrict__ w, const float* __restrict__ bias)
{
    __shared__ float itile[38][32];
    __shared__ float otile[32][33];
    int b = blockIdx.z, t0 = blockIdx.y * 32, f0 = blockIdx.x * 32;
    int tx = threadIdx.x & 31, ty = threadIdx.x >> 5;
    for (int i = threadIdx.x; i < 38 * 32; i += 256) {
        int r = i >> 5, c = i & 31;
        int t = t0 - 3 + r;
        itile[r][c] = (t >= 0 && t < 1024)
            ? bf2f(T3[((long long)(b * 1024 + t)) * 3072 + 2048 + f0 + c]) : 0.f;
    }
    __syncthreads();
    for (int r = ty; r < 32; r += 8) {
        const float* wr = w + (f0 + tx) * 7;
        float acc = bias[f0 + tx];
        #pragma unroll
        for (int k = 0; k < 7; k++) acc += itile[r + k][tx] * wr[k];
        otile[tx][r] = acc;
    }
    __syncthreads();
    for (int r = ty; r < 32; r += 8)
        out[((long long)(b * 1024 + f0 + r)) * 1024 + t0 + tx] = f2bf(otile[r][tx]);
}

// Q/K path: dconv along t on T3 q,k planes + pack S-GEMM operands:
//   Apk[z][t][0:256]=qc_q  Apk[z][t][256:512]=er^T[t]
//   Bpk[z][t][0:256]=qc_k  Bpk[z][t][256:512]=qc_q     (z = b*4+band)
__global__ __launch_bounds__(256)
void qkpack_k(const u16* __restrict__ T3, const float* __restrict__ w,
              const float* __restrict__ bias, const u16* __restrict__ ertb,
              u16* __restrict__ Apk, u16* __restrict__ Bpk)
{
    int idx = blockIdx.x * 256 + threadIdx.x;  // 4M
    int f = idx & 1023;
    int t = (idx >> 10) & 1023;
    int b = idx >> 20;
    int band = f >> 8, d = f & 255, z = (b << 2) | band;
    const float* wr = w + f * 7;
    float bq = bias[f];
    float aq = bq, ak = bq;
    #pragma unroll
    for (int k = 0; k < 7; k++) {
        int tt = t + k - 3;
        if (tt >= 0 && tt < 1024) {
            const u16* row = T3 + ((long long)(b << 10) + tt) * 3072 + f;
            float wk = wr[k];
            aq += bf2f(row[0]) * wk;
            ak += bf2f(row[1024]) * wk;
        }
    }
    long long base = (long long)z * 524288 + t * 512 + d;
    u16 qb = f2bf(aq);
    Apk[base] = qb;
    Apk[base + 256] = ertb[t * 256 + d];
    Bpk[base] = f2bf(ak);
    Bpk[base + 256] = qb;
}

// AOz (z,t,d) -> AO (b,t,f=band*256+d)
__global__ __launch_bounds__(256)
void aorepack_k(const u16* __restrict__ AOz, u16* __restrict__ AO)
{
    int idx = blockIdx.x * 256 + threadIdx.x;  // 4M
    int d = idx & 255;
    int t = (idx >> 8) & 1023;
    int z = idx >> 18;
    int b = z >> 2, band = z & 3;
    AO[((((long long)b << 10) + t) << 10) + (band << 8) + d] = AOz[idx];
}

// Fused weight cast: 10 fp32 sources -> contiguous bf16 W0.
struct CastArgs { const float* s[10]; };
__global__ __launch_bounds__(256)
void castall_k(CastArgs a, u16* __restrict__ dst)
{
    const int sz[10] = {2097152, 1048576, 524288, 1048576, 1048576,
                        1048576, 1048576, 1048576, 2097152, 2097152};
    int seg = blockIdx.y;
    int n = sz[seg];
    int base = 0;
    for (int i = 0; i < seg; i++) base += sz[i];
    int i4 = (blockIdx.x * 256 + threadIdx.x) * 4;
    if (i4 >= n) return;
    float4 v = *(const float4*)(a.s[seg] + i4);
    ushort4 o;
    o.x = f2bf(v.x); o.y = f2bf(v.y); o.z = f2bf(v.z); o.w = f2bf(v.w);
    *(ushort4*)(dst + base + i4) = o;
}

// er (256,1024) -> ert (1024,256) bf16
__global__ __launch_bounds__(256)
void ercast_k(const float* __restrict__ er, u16* __restrict__ ert)
{
    int idx = blockIdx.x * 256 + threadIdx.x;
    int j = idx >> 8, d = idx & 255;
    ert[idx] = f2bf(er[d * 1024 + j]);
}

// concat q_b,k_b,v_b -> qkvb (3072 fp32)
__global__ __launch_bounds__(256)
void biascat_k(const float* __restrict__ qb, const float* __restrict__ kb,
               const float* __restrict__ vb, float* __restrict__ dst)
{
    int i = blockIdx.x * 256 + threadIdx.x;
    if (i < 1024) dst[i] = qb[i];
    else if (i < 2048) dst[i] = kb[i - 1024];
    else if (i < 3072) dst[i] = vb[i - 2048];
}

__global__ __launch_bounds__(256)
void out_k(const float* __restrict__ src, const float* __restrict__ X,
           const float* __restrict__ ow, float* __restrict__ out)
{
    __shared__ float tile[32][33];
    int b = blockIdx.z;
    int f0 = blockIdx.y * 32, t0 = blockIdx.x * 32;
    for (int r = threadIdx.y; r < 32; r += 8)
        tile[r][threadIdx.x] = X[((long long)b * 1024 + t0 + r) * 1024 + f0 + threadIdx.x];
    __syncthreads();
    float w00 = ow[0], w01 = ow[1], w02 = ow[2];
    float w10 = ow[3], w11 = ow[4], w12 = ow[5];
    for (int r = threadIdx.y; r < 32; r += 8) {
        int f = f0 + r, t = t0 + threadIdx.x;
        float s0 = src[(((long long)b * 2 + 0) * 1025 + f) * 1024 + t];
        float s1 = src[(((long long)b * 2 + 1) * 1025 + f) * 1024 + t];
        float xv = tile[threadIdx.x][r];
        float v0 = fminf(fmaxf(w00 * s0 + w01 * s1 + w02 * xv, 0.f), 6.f) * (1.f / 6.f);
        float v1 = fminf(fmaxf(w10 * s0 + w11 * s1 + w12 * xv, 0.f), 6.f) * (1.f / 6.f);
        out[(((long long)b * 2 + 0) * 1025 + f) * 1024 + t] = v0;
        out[(((long long)b * 2 + 1) * 1025 + f) * 1024 + t] = v1;
        if (f == 1023) {
            out[(((long long)b * 2 + 0) * 1025 + 1024) * 1024 + t] = v0;
            out[(((long long)b * 2 + 1) * 1025 + 1024) * 1024 + t] = v1;
        }
    }
}

// ---------------------------------------------------------------------------
extern "C" void kernel_launch(void* const* d_in, const int* in_sizes, int n_in,
                              void* d_out, int out_size, void* d_ws, size_t ws_size,
                              hipStream_t stream)
{
    const float* src    = (const float*)d_in[0];
    const float* in_w   = (const float*)d_in[1];
    const float* ln1_g  = (const float*)d_in[2];
    const float* ln1_b  = (const float*)d_in[3];
    const float* glu_w  = (const float*)d_in[4];
    const float* ln2_g  = (const float*)d_in[5];
    const float* ln2_b  = (const float*)d_in[6];
    const float* c1L_dw = (const float*)d_in[7];
    const float* c1L_pw = (const float*)d_in[8];
    const float* c1R_dw = (const float*)d_in[9];
    const float* c1R_pw = (const float*)d_in[10];
    const float* ln3_g  = (const float*)d_in[11];
    const float* ln3_b  = (const float*)d_in[12];
    const float* c1M_dw = (const float*)d_in[13];
    const float* c1M_pw = (const float*)d_in[14];
    const float* ln4_g  = (const float*)d_in[15];
    const float* ln4_b  = (const float*)d_in[16];
    const float* q_w    = (const float*)d_in[17];
    const float* q_b    = (const float*)d_in[18];
    const float* qc_w   = (const float*)d_in[19];
    const float* qc_b   = (const float*)d_in[20];
    const float* k_w    = (const float*)d_in[21];
    const float* k_b    = (const float*)d_in[22];
    const float* v_w    = (const float*)d_in[23];
    const float* v_b    = (const float*)d_in[24];
    const float* o_w    = (const float*)d_in[25];
    const float* o_b    = (const float*)d_in[26];
    const float* er     = (const float*)d_in[27];
    const float* ln5_g  = (const float*)d_in[28];
    const float* ln5_b  = (const float*)d_in[29];
    const float* c2_w   = (const float*)d_in[30];
    const float* c3_w   = (const float*)d_in[31];
    const float* out_w  = (const float*)d_in[32];
    float* out = (float*)d_out;

    const size_t MB = 1ull << 20;
    if (ws_size < 162 * MB) return;
    char* wsb = (char*)d_ws;
    float* X   = (float*)(wsb + 0);         // 16 MB fp32 residual
    float* SB  = (float*)(wsb + 16 * MB);   // 16 MB fp32 hL+hR
    float* G   = (float*)(wsb + 32 * MB);   // 32 MB fp32 glu out
    u16* Apk   = (u16*)(wsb + 32 * MB);     // reuse: 16 MB S-GEMM A' (z,t,512)
    u16* Bpk   = (u16*)(wsb + 48 * MB);     //        16 MB S-GEMM B'
    u16* Hbf   = (u16*)(wsb + 64 * MB);     // 8 MB ln outputs
    u16* T1bf  = (u16*)(wsb + 72 * MB);     // 8 MB dconv temps (pre-QKV)
    u16* T3    = (u16*)(wsb + 72 * MB);     // 24 MB QKV (4096x3072)
    u16* AOz   = (u16*)(wsb + 72 * MB);     // reuse: 8 MB AO (z,t,256)
    u16* AO    = (u16*)(wsb + 80 * MB);     // reuse: 8 MB AO (B,T,F)
    u16* T2bf  = (u16*)(wsb + 96 * MB);     // 8 MB dconvF out (c1L)
    u16* Vt    = (u16*)(wsb + 96 * MB);     // reuse: 8 MB V^T (b,f,t)
    u16* Sbf   = (u16*)(wsb + 104 * MB);    // 32 MB scores (16,1024,1024)
    u16* Gbf   = (u16*)(wsb + 104 * MB);    // reuse: 16 MB ffn mid
    u16* W0    = (u16*)(wsb + 136 * MB);    // bf16 weights

    u16* glu_wb  = W0;
    u16* c1L_pwb = W0 + 2097152;
    u16* c1R_pwb = W0 + 3145728;
    u16* c1M_pwb = W0 + 3670016;
    u16* qkv_wb  = W0 + 4718592;   // q,k,v contiguous (3072 x 1024)
    u16* o_wb    = W0 + 7864320;
    u16* c2_wb   = W0 + 8912896;
    u16* c3_wb   = W0 + 11010048;
    u16* ertb    = W0 + 13107200;  // 262144
    float* qkvb  = (float*)(W0 + 13369344);  // 3072 fp32

    const dim3 blk256(256);
    const dim3 tgrid(32, 32, NB);
    const dim3 tblk(32, 8);
    const int EW = 16384;  // 4M / 256

    // --- weights ---
    CastArgs ca;
    ca.s[0] = glu_w;  ca.s[1] = c1L_pw; ca.s[2] = c1R_pw; ca.s[3] = c1M_pw;
    ca.s[4] = q_w;    ca.s[5] = k_w;    ca.s[6] = v_w;    ca.s[7] = o_w;
    ca.s[8] = c2_w;   ca.s[9] = c3_w;
    castall_k<<<dim3(2048, 10), blk256, 0, stream>>>(ca, W0);
    ercast_k<<<1024, blk256, 0, stream>>>(er, ertb);
    biascat_k<<<12, blk256, 0, stream>>>(q_b, k_b, v_b, qkvb);

    // 1. input projection
    inproj_k<<<tgrid, tblk, 0, stream>>>(src, in_w, X);
    // 2-3. h = ln1(x); g = h @ glu_w^T (4096x2048x1024), 1024 blocks
    ln_bf_k<<<4096, blk256, 0, stream>>>(X, Hbf, ln1_g, ln1_b);
    gemm_bf<128, 64, 0, false, false><<<dim3(32, 32, 1), blk256, 0, stream>>>(
        Hbf, glu_wb, G, 1024, 1024, 1024, 2048, 0, 0, 0, nullptr, 1.f);
    // 4. x += glu
    glu_k<<<4096, blk256, 0, stream>>>(G, X);
    // 5. h = ln2(x)
    ln_bf_k<<<4096, blk256, 0, stream>>>(X, Hbf, ln2_g, ln2_b);
    // 6-7. hL = relu(c1L_pw · dconvF(h)), 1024 blocks
    dconvF_t_k<<<tgrid, blk256, 0, stream>>>(Hbf, T2bf, c1L_dw);
    gemm_bf<64, 64, 1, false, false><<<dim3(16, 16, NB), blk256, 0, stream>>>(
        c1L_pwb, T2bf, SB, 1024, 1024, 1024, 1024, 0, M1, M1, nullptr, 1.f);
    // 8-9. SB[:, :512] += relu(dconvT(h) @ c1R_pw^T), 512 blocks
    dconvT_bf_k<<<EW, blk256, 0, stream>>>(Hbf, T1bf, c1R_dw);
    gemm_bf<64, 64, 1, true, false><<<dim3(8, 64, 1), blk256, 0, stream>>>(
        T1bf, c1R_pwb, SB, 1024, 1024, 1024, 1024, 0, 0, 0, nullptr, 1.f);
    // 10-12. h = ln3(SB); x += dconvT(h) @ c1M_pw^T, 1024 blocks
    ln_bf_k<<<4096, blk256, 0, stream>>>(SB, Hbf, ln3_g, ln3_b);
    dconvT_bf_k<<<EW, blk256, 0, stream>>>(Hbf, T1bf, c1M_dw);
    gemm_bf<64, 64, 0, true, false><<<dim3(16, 64, 1), blk256, 0, stream>>>(
        T1bf, c1M_pwb, X, 1024, 1024, 1024, 1024, 0, 0, 0, nullptr, 1.f);
    // 13. h = ln4(x)
    ln_bf_k<<<4096, blk256, 0, stream>>>(X, Hbf, ln4_g, ln4_b);
    // 14. fused QKV GEMM (4096x3072x1024) -> T3 bf16, 768 blocks
    gemm_bf<128, 128, 0, false, true><<<dim3(24, 32, 1), blk256, 0, stream>>>(
        Hbf, qkv_wb, T3, 1024, 1024, 1024, 3072, 0, 0, 0, qkvb, 1.f);
    // 15-16. qc convs: pack S operands; V transposed
    qkpack_k<<<EW, blk256, 0, stream>>>(T3, qc_w, qc_b, ertb, Apk, Bpk);
    vconv_t_k<<<tgrid, blk256, 0, stream>>>(T3, Vt, qc_w, qc_b);
    // 17. S = (QK^T + rel-pos)/32, 16 planes, K=512, 1024 blocks
    gemm_bf<128, 128, 0, false, true><<<dim3(8, 8, 16), blk256, 0, stream>>>(
        Apk, Bpk, Sbf, 512, 512, 512, 1024, 524288, 524288, M1,
        nullptr, 0.03125f);
    // 18. softmax (16384 rows)
    softmax_bf_k<<<16384, blk256, 0, stream>>>(Sbf);
    // 19-20. AO = S @ V (per z: 1024x256x1024), 1024 blocks; repack
    gemm_bf<64, 64, 0, false, true><<<dim3(4, 16, 16), blk256, 0, stream>>>(
        Sbf, Vt, AOz, 1024, 1024, 1024, 256, M1, 262144, 262144,
        nullptr, 1.f);
    aorepack_k<<<EW, blk256, 0, stream>>>(AOz, AO);
    // 21. x += AO @ o_w^T + o_b, 1024 blocks
    gemm_bf<64, 64, 0, true, false><<<dim3(16, 64, 1), blk256, 0, stream>>>(
        AO, o_wb, X, 1024, 1024, 1024, 1024, 0, 0, 0, o_b, 1.f);
    // 22-23. h = ln5(x); mid = relu(h @ c2_w^T)^2, 1024 blocks
    ln_bf_k<<<4096, blk256, 0, stream>>>(X, Hbf, ln5_g, ln5_b);
    gemm_bf<128, 64, 2, false, true><<<dim3(32, 32, 1), blk256, 0, stream>>>(
        Hbf, c2_wb, Gbf, 1024, 1024, 1024, 2048, 0, 0, 0, nullptr, 1.f);
    // 24. x += mid @ c3_w^T, 1024 blocks
    gemm_bf<64, 64, 0, true, false><<<dim3(16, 64, 1), blk256, 0, stream>>>(
        Gbf, c3_wb, X, 2048, 2048, 2048, 1024, 0, 0, 0, nullptr, 1.f);
    // 25. output head
    out_k<<<tgrid, tblk, 0, stream>>>(src, X, out_w, out);
}

// Round 6
// 622.570 us; speedup vs baseline: 1.2993x; 1.2993x over previous
//
#include <hip/hip_runtime.h>
#include <math.h>

// ---------------------------------------------------------------------------
// FrameTransformer — GEMM v4: coalesced staging (16 rows x 64B per
// global_load_lds, the R3 pattern) + swizzled LDS layout that keeps
// ds_read_b128 fragment reads conflict-free:
//   addr(row,kc8) = ((row>>4)*2 + (kc8>>2))*1024B + (row&15)*64 + (kc8&3)*16
// R4/R5 post-mortem: kc-major staging had 64 lanes x 16B @ 2KB stride =
// 64 cache lines per inst -> latency-bound (MfmaUtil 8.7 despite 4 blk/CU).
// ---------------------------------------------------------------------------

typedef unsigned short u16;
typedef __attribute__((ext_vector_type(4))) float floatx4;
typedef __attribute__((ext_vector_type(8))) short short8;

#define NB 4
static const long long M1 = 1024LL * 1024LL;

__device__ __forceinline__ float bf2f(u16 h) {
    union { unsigned int u; float f; } v;
    v.u = ((unsigned int)h) << 16;
    return v.f;
}
__device__ __forceinline__ u16 f2bf(float x) {
    union { float f; unsigned int u; } v;
    v.f = x;
    unsigned int r = (v.u + 0x7FFFu + ((v.u >> 16) & 1u)) >> 16;
    return (u16)r;
}

__device__ __forceinline__ void async_cp16(const u16* g, u16* lds) {
    __builtin_amdgcn_global_load_lds(
        (const __attribute__((address_space(1))) unsigned int*)g,
        (__attribute__((address_space(3))) unsigned int*)lds, 16, 0, 0);
}

__device__ __forceinline__ float block_sum(float v) {
    __shared__ float sd[4];
    #pragma unroll
    for (int off = 32; off; off >>= 1) v += __shfl_down(v, off, 64);
    int lane = threadIdx.x & 63, wid = threadIdx.x >> 6;
    __syncthreads();
    if (lane == 0) sd[wid] = v;
    __syncthreads();
    return sd[0] + sd[1] + sd[2] + sd[3];
}
__device__ __forceinline__ float block_max(float v) {
    __shared__ float sd[4];
    #pragma unroll
    for (int off = 32; off; off >>= 1) v = fmaxf(v, __shfl_down(v, off, 64));
    int lane = threadIdx.x & 63, wid = threadIdx.x >> 6;
    __syncthreads();
    if (lane == 0) sd[wid] = v;
    __syncthreads();
    return fmaxf(fmaxf(sd[0], sd[1]), fmaxf(sd[2], sd[3]));
}

// ---------------------------------------------------------------------------
// bf16 NT GEMM v4: C[M,N] (op)= act( scale*(A·B^T + bias) )
// A [M,K] bf16, B [N,K] bf16, row-major. Tile BM x BN, BK=64, 4 waves 2x2,
// wave tile (BM/2)x(BN/2). Staging: each inst = 16 rows x 64B coalesced.
// LDS: 1KB blocks indexed (rowgroup, kb), inside: (row&15)*64 + kchunk*16.
// XCD swizzle: id&7 = m-stripe residue. M%BM==0, N%BN==0, K%64==0, gy%8==0.
// ---------------------------------------------------------------------------
template<int BM, int BN, int ACT, bool ACCUM, bool OBF>
__global__ __launch_bounds__(256)
void gemm_bf(const u16* __restrict__ A, const u16* __restrict__ B,
             void* __restrict__ Cv, int K, int lda, int ldb, int ldc,
             long long sAz, long long sBz, long long sCz,
             const float* __restrict__ bias, float scale)
{
    constexpr int MI = BM / 32;        // a-frags per wave
    constexpr int NJ = BN / 32;        // b-frags per wave

    A += (long long)blockIdx.z * sAz;
    B += (long long)blockIdx.z * sBz;
    const long long zc = (long long)blockIdx.z * sCz;

    __shared__ u16 As[BM * 64];        // BM/8 KB, swizzled blocks of 1KB
    __shared__ u16 Bs[BN * 64];

    // XCD-aware swizzle (round-robin block->XCD by linear id)
    const int id = blockIdx.x + gridDim.x * blockIdx.y;
    const int bx = (id >> 3) % gridDim.x;
    const int by = (id & 7) + 8 * ((id >> 3) / gridDim.x);
    const int m0 = by * BM;
    const int n0 = bx * BN;

    const int tid  = threadIdx.x;
    const int lane = tid & 63;
    const int w    = tid >> 6;
    const int wm   = (w >> 1) * (BM / 2);
    const int wn   = (w & 1) * (BN / 2);

    // staging geometry: lane covers row = rg*16 + (lane>>2), 16B chunk lane&3
    const int srow = lane >> 2;
    const int scol = (lane & 3) * 8;

    floatx4 acc[MI][NJ];
    #pragma unroll
    for (int i = 0; i < MI; i++)
        #pragma unroll
        for (int j = 0; j < NJ; j++)
            acc[i][j] = floatx4{0.f, 0.f, 0.f, 0.f};

    for (int k0 = 0; k0 < K; k0 += 64) {
        #pragma unroll
        for (int r = 0; r < BM / 32; r++) {
            const int inst = w * (BM / 32) + r;
            const int rg = inst >> 1, kb = inst & 1;
            async_cp16(A + (long long)(m0 + rg * 16 + srow) * lda + k0 + kb * 32 + scol,
                       &As[(rg * 2 + kb) * 512]);
        }
        #pragma unroll
        for (int r = 0; r < BN / 32; r++) {
            const int inst = w * (BN / 32) + r;
            const int rg = inst >> 1, kb = inst & 1;
            async_cp16(B + (long long)(n0 + rg * 16 + srow) * ldb + k0 + kb * 32 + scol,
                       &Bs[(rg * 2 + kb) * 512]);
        }
        __syncthreads();

        #pragma unroll
        for (int s = 0; s < 2; s++) {
            short8 a[MI], b[NJ];
            const int fr = lane & 15;
            const int q  = lane >> 4;
            const int go = (fr * 4 + q) * 8;   // granule offset in u16
            #pragma unroll
            for (int i = 0; i < MI; i++)
                a[i] = *(const short8*)&As[(((wm >> 4) + i) * 2 + s) * 512 + go];
            #pragma unroll
            for (int j = 0; j < NJ; j++)
                b[j] = *(const short8*)&Bs[(((wn >> 4) + j) * 2 + s) * 512 + go];
            #pragma unroll
            for (int i = 0; i < MI; i++)
                #pragma unroll
                for (int j = 0; j < NJ; j++)
                    acc[i][j] = __builtin_amdgcn_mfma_f32_16x16x32_bf16(
                        a[i], b[j], acc[i][j], 0, 0, 0);
        }
        __syncthreads();
    }

    float* Cf = (float*)Cv;
    u16*  Cb  = (u16*)Cv;
    const int cn    = n0 + wn + (lane & 15);
    const int rbase = m0 + wm + (lane >> 4) * 4;
    float bj[NJ];
    #pragma unroll
    for (int j = 0; j < NJ; j++) bj[j] = bias ? bias[cn + j * 16] : 0.f;

    #pragma unroll
    for (int i = 0; i < MI; i++) {
        #pragma unroll
        for (int r = 0; r < 4; r++) {
            const int m = rbase + i * 16 + r;
            #pragma unroll
            for (int j = 0; j < NJ; j++) {
                const int n = cn + j * 16;
                float v = (acc[i][j][r] + bj[j]) * scale;
                if (ACT == 1) v = fmaxf(v, 0.f);
                else if (ACT == 2) { v = fmaxf(v, 0.f); v = v * v; }
                const long long ci = zc + (long long)m * ldc + n;
                if (OBF)        Cb[ci] = f2bf(v);
                else if (ACCUM) Cf[ci] += v;
                else            Cf[ci] = v;
            }
        }
    }
}

// ---------------------------------------------------------------------------
__global__ __launch_bounds__(256)
void ln_bf_k(const float* __restrict__ in, u16* __restrict__ out,
             const float* __restrict__ g, const float* __restrict__ b)
{
    long long row = blockIdx.x;
    const float4* ip = (const float4*)(in + (row << 10));
    int tid = threadIdx.x;
    float4 v = ip[tid];
    float s = v.x + v.y + v.z + v.w;
    s = block_sum(s);
    float mean = s * (1.f / 1024.f);
    float dx = v.x - mean, dy = v.y - mean, dz = v.z - mean, dw = v.w - mean;
    float s2 = dx * dx + dy * dy + dz * dz + dw * dw;
    s2 = block_sum(s2);
    float inv = rsqrtf(s2 * (1.f / 1024.f) + 1e-5f);
    float4 gg = ((const float4*)g)[tid];
    float4 bb = ((const float4*)b)[tid];
    ushort4 o;
    o.x = f2bf(dx * inv * gg.x + bb.x);
    o.y = f2bf(dy * inv * gg.y + bb.y);
    o.z = f2bf(dz * inv * gg.z + bb.z);
    o.w = f2bf(dw * inv * gg.w + bb.w);
    ((ushort4*)(out + (row << 10)))[tid] = o;
}

__global__ __launch_bounds__(256)
void softmax_bf_k(u16* __restrict__ S)
{
    long long row = blockIdx.x;
    u16* p = S + (row << 10);
    int tid = threadIdx.x;
    ushort4 u = ((ushort4*)p)[tid];
    float x0 = bf2f(u.x), x1 = bf2f(u.y), x2 = bf2f(u.z), x3 = bf2f(u.w);
    float m = fmaxf(fmaxf(x0, x1), fmaxf(x2, x3));
    m = block_max(m);
    x0 = expf(x0 - m); x1 = expf(x1 - m); x2 = expf(x2 - m); x3 = expf(x3 - m);
    float s = x0 + x1 + x2 + x3;
    s = block_sum(s);
    float r = 1.f / s;
    u.x = f2bf(x0 * r); u.y = f2bf(x1 * r); u.z = f2bf(x2 * r); u.w = f2bf(x3 * r);
    ((ushort4*)p)[tid] = u;
}

__global__ __launch_bounds__(256)
void inproj_k(const float* __restrict__ src, const float* __restrict__ inw,
              float* __restrict__ X)
{
    __shared__ float tile[32][33];
    int b = blockIdx.z;
    int f0 = blockIdx.y * 32, t0 = blockIdx.x * 32;
    float w0 = inw[0], w1 = inw[1];
    for (int r = threadIdx.y; r < 32; r += 8) {
        int f = f0 + r, t = t0 + threadIdx.x;
        float s0 = src[(((long long)b * 2 + 0) * 1025 + f) * 1024 + t];
        float s1 = src[(((long long)b * 2 + 1) * 1025 + f) * 1024 + t];
        tile[r][threadIdx.x] = w0 * s0 + w1 * s1;
    }
    __syncthreads();
    for (int r = threadIdx.y; r < 32; r += 8)
        X[((long long)b * 1024 + t0 + r) * 1024 + f0 + threadIdx.x] = tile[threadIdx.x][r];
}

__global__ __launch_bounds__(256)
void glu_k(const float* __restrict__ G, float* __restrict__ X)
{
    int idx = blockIdx.x * 256 + threadIdx.x;   // 1M float4 groups
    int f4 = idx & 255;
    long long row = idx >> 8;
    float4 a = *(const float4*)(G + row * 2048 + f4 * 4);
    float4 s = *(const float4*)(G + row * 2048 + 1024 + f4 * 4);
    float4* xp = (float4*)(X + row * 1024 + f4 * 4);
    float4 x = *xp;
    x.x += a.x / (1.f + expf(-s.x));
    x.y += a.y / (1.f + expf(-s.y));
    x.z += a.z / (1.f + expf(-s.z));
    x.w += a.w / (1.f + expf(-s.w));
    *xp = x;
}

// dconv along f (contiguous), channels=t, k=11 pad 5, transposed out[b][f][t].
__global__ __launch_bounds__(256)
void dconvF_t_k(const u16* __restrict__ in, u16* __restrict__ out,
                const float* __restrict__ w)
{
    __shared__ float itile[32][44];
    __shared__ float otile[32][33];
    int b = blockIdx.z, t0 = blockIdx.y * 32, f0 = blockIdx.x * 32;
    int tx = threadIdx.x & 31, ty = threadIdx.x >> 5;
    for (int r = ty; r < 32; r += 8)
        for (int c = tx; c < 42; c += 32) {
            int f = f0 - 5 + c;
            itile[r][c] = (f >= 0 && f < 1024)
                ? bf2f(in[((long long)(b * 1024 + t0 + r)) * 1024 + f]) : 0.f;
        }
    __syncthreads();
    for (int r = ty; r < 32; r += 8) {
        const float* wr = w + (t0 + r) * 11;
        float acc = 0.f;
        #pragma unroll
        for (int k = 0; k < 11; k++) acc += itile[r][tx + k] * wr[k];
        otile[tx][r] = acc;
    }
    __syncthreads();
    for (int r = ty; r < 32; r += 8)
        out[((long long)(b * 1024 + f0 + r)) * 1024 + t0 + tx] = f2bf(otile[r][tx]);
}

// dconv along t (strided), channels=f, k=7 pad 3, bf16 (B,T,F)->(B,T,F).
__global__ __launch_bounds__(256)
void dconvT_bf_k(const u16* __restrict__ in, u16* __restrict__ out,
                 const float* __restrict__ w)
{
    int idx = blockIdx.x * 256 + threadIdx.x;
    int f = idx & 1023;
    int bt = idx >> 10;
    int t = bt & 1023;
    int b = bt >> 10;
    const float* wr = w + f * 7;
    float acc = 0.f;
    #pragma unroll
    for (int k = 0; k < 7; k++) {
        int tt = t + k - 3;
        if (tt >= 0 && tt < 1024)
            acc += bf2f(in[(((long long)b << 10) + tt) * 1024 + f]) * wr[k];
    }
    out[idx] = f2bf(acc);
}

// V path: dconv along t on T3 v-plane (stride 3072, offset 2048) + bias,
// transposed out Vt[b][f][t].
__global__ __launch_bounds__(256)
void vconv_t_k(const u16* __restrict__ T3, u16* __restrict__ out,
               const float* __restrict__ w, const float* __restrict__ bias)
{
    __shared__ float itile[38][32];
    __shared__ float otile[32][33];
    int b = blockIdx.z, t0 = blockIdx.y * 32, f0 = blockIdx.x * 32;
    int tx = threadIdx.x & 31, ty = threadIdx.x >> 5;
    for (int i = threadIdx.x; i < 38 * 32; i += 256) {
        int r = i >> 5, c = i & 31;
        int t = t0 - 3 + r;
        itile[r][c] = (t >= 0 && t < 1024)
            ? bf2f(T3[((long long)(b * 1024 + t)) * 3072 + 2048 + f0 + c]) : 0.f;
    }
    __syncthreads();
    for (int r = ty; r < 32; r += 8) {
        const float* wr = w + (f0 + tx) * 7;
        float acc = bias[f0 + tx];
        #pragma unroll
        for (int k = 0; k < 7; k++) acc += itile[r + k][tx] * wr[k];
        otile[tx][r] = acc;
    }
    __syncthreads();
    for (int r = ty; r < 32; r += 8)
        out[((long long)(b * 1024 + f0 + r)) * 1024 + t0 + tx] = f2bf(otile[r][tx]);
}

// Q/K path: dconv along t on T3 q,k planes + pack S-GEMM operands:
//   Apk[z][t][0:256]=qc_q  Apk[z][t][256:512]=er^T[t]
//   Bpk[z][t][0:256]=qc_k  Bpk[z][t][256:512]=qc_q     (z = b*4+band)
__global__ __launch_bounds__(256)
void qkpack_k(const u16* __restrict__ T3, const float* __restrict__ w,
              const float* __restrict__ bias, const u16* __restrict__ ertb,
              u16* __restrict__ Apk, u16* __restrict__ Bpk)
{
    int idx = blockIdx.x * 256 + threadIdx.x;  // 4M
    int f = idx & 1023;
    int t = (idx >> 10) & 1023;
    int b = idx >> 20;
    int band = f >> 8, d = f & 255, z = (b << 2) | band;
    const float* wr = w + f * 7;
    float bq = bias[f];
    float aq = bq, ak = bq;
    #pragma unroll
    for (int k = 0; k < 7; k++) {
        int tt = t + k - 3;
        if (tt >= 0 && tt < 1024) {
            const u16* row = T3 + ((long long)(b << 10) + tt) * 3072 + f;
            float wk = wr[k];
            aq += bf2f(row[0]) * wk;
            ak += bf2f(row[1024]) * wk;
        }
    }
    long long base = (long long)z * 524288 + t * 512 + d;
    u16 qb = f2bf(aq);
    Apk[base] = qb;
    Apk[base + 256] = ertb[t * 256 + d];
    Bpk[base] = f2bf(ak);
    Bpk[base + 256] = qb;
}

// AOz (z,t,d) -> AO (b,t,f=band*256+d)
__global__ __launch_bounds__(256)
void aorepack_k(const u16* __restrict__ AOz, u16* __restrict__ AO)
{
    int idx = blockIdx.x * 256 + threadIdx.x;  // 4M
    int d = idx & 255;
    int t = (idx >> 8) & 1023;
    int z = idx >> 18;
    int b = z >> 2, band = z & 3;
    AO[((((long long)b << 10) + t) << 10) + (band << 8) + d] = AOz[idx];
}

// Fused weight cast: 10 fp32 sources -> contiguous bf16 W0.
struct CastArgs { const float* s[10]; };
__global__ __launch_bounds__(256)
void castall_k(CastArgs a, u16* __restrict__ dst)
{
    const int sz[10] = {2097152, 1048576, 524288, 1048576, 1048576,
                        1048576, 1048576, 1048576, 2097152, 2097152};
    int seg = blockIdx.y;
    int n = sz[seg];
    int base = 0;
    for (int i = 0; i < seg; i++) base += sz[i];
    int i4 = (blockIdx.x * 256 + threadIdx.x) * 4;
    if (i4 >= n) return;
    float4 v = *(const float4*)(a.s[seg] + i4);
    ushort4 o;
    o.x = f2bf(v.x); o.y = f2bf(v.y); o.z = f2bf(v.z); o.w = f2bf(v.w);
    *(ushort4*)(dst + base + i4) = o;
}

// er (256,1024) -> ert (1024,256) bf16
__global__ __launch_bounds__(256)
void ercast_k(const float* __restrict__ er, u16* __restrict__ ert)
{
    int idx = blockIdx.x * 256 + threadIdx.x;
    int j = idx >> 8, d = idx & 255;
    ert[idx] = f2bf(er[d * 1024 + j]);
}

// concat q_b,k_b,v_b -> qkvb (3072 fp32)
__global__ __launch_bounds__(256)
void biascat_k(const float* __restrict__ qb, const float* __restrict__ kb,
               const float* __restrict__ vb, float* __restrict__ dst)
{
    int i = blockIdx.x * 256 + threadIdx.x;
    if (i < 1024) dst[i] = qb[i];
    else if (i < 2048) dst[i] = kb[i - 1024];
    else if (i < 3072) dst[i] = vb[i - 2048];
}

__global__ __launch_bounds__(256)
void out_k(const float* __restrict__ src, const float* __restrict__ X,
           const float* __restrict__ ow, float* __restrict__ out)
{
    __shared__ float tile[32][33];
    int b = blockIdx.z;
    int f0 = blockIdx.y * 32, t0 = blockIdx.x * 32;
    for (int r = threadIdx.y; r < 32; r += 8)
        tile[r][threadIdx.x] = X[((long long)b * 1024 + t0 + r) * 1024 + f0 + threadIdx.x];
    __syncthreads();
    float w00 = ow[0], w01 = ow[1], w02 = ow[2];
    float w10 = ow[3], w11 = ow[4], w12 = ow[5];
    for (int r = threadIdx.y; r < 32; r += 8) {
        int f = f0 + r, t = t0 + threadIdx.x;
        float s0 = src[(((long long)b * 2 + 0) * 1025 + f) * 1024 + t];
        float s1 = src[(((long long)b * 2 + 1) * 1025 + f) * 1024 + t];
        float xv = tile[threadIdx.x][r];
        float v0 = fminf(fmaxf(w00 * s0 + w01 * s1 + w02 * xv, 0.f), 6.f) * (1.f / 6.f);
        float v1 = fminf(fmaxf(w10 * s0 + w11 * s1 + w12 * xv, 0.f), 6.f) * (1.f / 6.f);
        out[(((long long)b * 2 + 0) * 1025 + f) * 1024 + t] = v0;
        out[(((long long)b * 2 + 1) * 1025 + f) * 1024 + t] = v1;
        if (f == 1023) {
            out[(((long long)b * 2 + 0) * 1025 + 1024) * 1024 + t] = v0;
            out[(((long long)b * 2 + 1) * 1025 + 1024) * 1024 + t] = v1;
        }
    }
}

// ---------------------------------------------------------------------------
extern "C" void kernel_launch(void* const* d_in, const int* in_sizes, int n_in,
                              void* d_out, int out_size, void* d_ws, size_t ws_size,
                              hipStream_t stream)
{
    const float* src    = (const float*)d_in[0];
    const float* in_w   = (const float*)d_in[1];
    const float* ln1_g  = (const float*)d_in[2];
    const float* ln1_b  = (const float*)d_in[3];
    const float* glu_w  = (const float*)d_in[4];
    const float* ln2_g  = (const float*)d_in[5];
    const float* ln2_b  = (const float*)d_in[6];
    const float* c1L_dw = (const float*)d_in[7];
    const float* c1L_pw = (const float*)d_in[8];
    const float* c1R_dw = (const float*)d_in[9];
    const float* c1R_pw = (const float*)d_in[10];
    const float* ln3_g  = (const float*)d_in[11];
    const float* ln3_b  = (const float*)d_in[12];
    const float* c1M_dw = (const float*)d_in[13];
    const float* c1M_pw = (const float*)d_in[14];
    const float* ln4_g  = (const float*)d_in[15];
    const float* ln4_b  = (const float*)d_in[16];
    const float* q_w    = (const float*)d_in[17];
    const float* q_b    = (const float*)d_in[18];
    const float* qc_w   = (const float*)d_in[19];
    const float* qc_b   = (const float*)d_in[20];
    const float* k_w    = (const float*)d_in[21];
    const float* k_b    = (const float*)d_in[22];
    const float* v_w    = (const float*)d_in[23];
    const float* v_b    = (const float*)d_in[24];
    const float* o_w    = (const float*)d_in[25];
    const float* o_b    = (const float*)d_in[26];
    const float* er     = (const float*)d_in[27];
    const float* ln5_g  = (const float*)d_in[28];
    const float* ln5_b  = (const float*)d_in[29];
    const float* c2_w   = (const float*)d_in[30];
    const float* c3_w   = (const float*)d_in[31];
    const float* out_w  = (const float*)d_in[32];
    float* out = (float*)d_out;

    const size_t MB = 1ull << 20;
    if (ws_size < 162 * MB) return;
    char* wsb = (char*)d_ws;
    float* X   = (float*)(wsb + 0);         // 16 MB fp32 residual
    float* SB  = (float*)(wsb + 16 * MB);   // 16 MB fp32 hL+hR
    float* G   = (float*)(wsb + 32 * MB);   // 32 MB fp32 glu out
    u16* Apk   = (u16*)(wsb + 32 * MB);     // reuse: 16 MB S-GEMM A' (z,t,512)
    u16* Bpk   = (u16*)(wsb + 48 * MB);     //        16 MB S-GEMM B'
    u16* Hbf   = (u16*)(wsb + 64 * MB);     // 8 MB ln outputs
    u16* T1bf  = (u16*)(wsb + 72 * MB);     // 8 MB dconv temps (pre-QKV)
    u16* T3    = (u16*)(wsb + 72 * MB);     // 24 MB QKV (4096x3072)
    u16* AOz   = (u16*)(wsb + 72 * MB);     // reuse: 8 MB AO (z,t,256)
    u16* AO    = (u16*)(wsb + 80 * MB);     // reuse: 8 MB AO (B,T,F)
    u16* T2bf  = (u16*)(wsb + 96 * MB);     // 8 MB dconvF out (c1L)
    u16* Vt    = (u16*)(wsb + 96 * MB);     // reuse: 8 MB V^T (b,f,t)
    u16* Sbf   = (u16*)(wsb + 104 * MB);    // 32 MB scores (16,1024,1024)
    u16* Gbf   = (u16*)(wsb + 104 * MB);    // reuse: 16 MB ffn mid
    u16* W0    = (u16*)(wsb + 136 * MB);    // bf16 weights

    u16* glu_wb  = W0;
    u16* c1L_pwb = W0 + 2097152;
    u16* c1R_pwb = W0 + 3145728;
    u16* c1M_pwb = W0 + 3670016;
    u16* qkv_wb  = W0 + 4718592;   // q,k,v contiguous (3072 x 1024)
    u16* o_wb    = W0 + 7864320;
    u16* c2_wb   = W0 + 8912896;
    u16* c3_wb   = W0 + 11010048;
    u16* ertb    = W0 + 13107200;  // 262144
    float* qkvb  = (float*)(W0 + 13369344);  // 3072 fp32

    const dim3 blk256(256);
    const dim3 tgrid(32, 32, NB);
    const dim3 tblk(32, 8);
    const int EW = 16384;  // 4M / 256

    // --- weights ---
    CastArgs ca;
    ca.s[0] = glu_w;  ca.s[1] = c1L_pw; ca.s[2] = c1R_pw; ca.s[3] = c1M_pw;
    ca.s[4] = q_w;    ca.s[5] = k_w;    ca.s[6] = v_w;    ca.s[7] = o_w;
    ca.s[8] = c2_w;   ca.s[9] = c3_w;
    castall_k<<<dim3(2048, 10), blk256, 0, stream>>>(ca, W0);
    ercast_k<<<1024, blk256, 0, stream>>>(er, ertb);
    biascat_k<<<12, blk256, 0, stream>>>(q_b, k_b, v_b, qkvb);

    // 1. input projection
    inproj_k<<<tgrid, tblk, 0, stream>>>(src, in_w, X);
    // 2-3. h = ln1(x); g = h @ glu_w^T (4096x2048x1024), 512 blocks
    ln_bf_k<<<4096, blk256, 0, stream>>>(X, Hbf, ln1_g, ln1_b);
    gemm_bf<128, 128, 0, false, false><<<dim3(16, 32, 1), blk256, 0, stream>>>(
        Hbf, glu_wb, G, 1024, 1024, 1024, 2048, 0, 0, 0, nullptr, 1.f);
    // 4. x += glu
    glu_k<<<4096, blk256, 0, stream>>>(G, X);
    // 5. h = ln2(x)
    ln_bf_k<<<4096, blk256, 0, stream>>>(X, Hbf, ln2_g, ln2_b);
    // 6-7. hL = relu(c1L_pw · dconvF(h)), 512 blocks
    dconvF_t_k<<<tgrid, blk256, 0, stream>>>(Hbf, T2bf, c1L_dw);
    gemm_bf<128, 64, 1, false, false><<<dim3(16, 8, NB), blk256, 0, stream>>>(
        c1L_pwb, T2bf, SB, 1024, 1024, 1024, 1024, 0, M1, M1, nullptr, 1.f);
    // 8-9. SB[:, :512] += relu(dconvT(h) @ c1R_pw^T), 256 blocks
    dconvT_bf_k<<<EW, blk256, 0, stream>>>(Hbf, T1bf, c1R_dw);
    gemm_bf<128, 64, 1, true, false><<<dim3(8, 32, 1), blk256, 0, stream>>>(
        T1bf, c1R_pwb, SB, 1024, 1024, 1024, 1024, 0, 0, 0, nullptr, 1.f);
    // 10-12. h = ln3(SB); x += dconvT(h) @ c1M_pw^T, 512 blocks
    ln_bf_k<<<4096, blk256, 0, stream>>>(SB, Hbf, ln3_g, ln3_b);
    dconvT_bf_k<<<EW, blk256, 0, stream>>>(Hbf, T1bf, c1M_dw);
    gemm_bf<128, 64, 0, true, false><<<dim3(16, 32, 1), blk256, 0, stream>>>(
        T1bf, c1M_pwb, X, 1024, 1024, 1024, 1024, 0, 0, 0, nullptr, 1.f);
    // 13. h = ln4(x)
    ln_bf_k<<<4096, blk256, 0, stream>>>(X, Hbf, ln4_g, ln4_b);
    // 14. fused QKV GEMM (4096x3072x1024) -> T3 bf16, 768 blocks
    gemm_bf<128, 128, 0, false, true><<<dim3(24, 32, 1), blk256, 0, stream>>>(
        Hbf, qkv_wb, T3, 1024, 1024, 1024, 3072, 0, 0, 0, qkvb, 1.f);
    // 15-16. qc convs: pack S operands; V transposed
    qkpack_k<<<EW, blk256, 0, stream>>>(T3, qc_w, qc_b, ertb, Apk, Bpk);
    vconv_t_k<<<tgrid, blk256, 0, stream>>>(T3, Vt, qc_w, qc_b);
    // 17. S = (QK^T + rel-pos)/32, 16 planes, K=512, 1024 blocks
    gemm_bf<128, 128, 0, false, true><<<dim3(8, 8, 16), blk256, 0, stream>>>(
        Apk, Bpk, Sbf, 512, 512, 512, 1024, 524288, 524288, M1,
        nullptr, 0.03125f);
    // 18. softmax (16384 rows)
    softmax_bf_k<<<16384, blk256, 0, stream>>>(Sbf);
    // 19-20. AO = S @ V (per z: 1024x256x1024), 512 blocks; repack
    gemm_bf<128, 64, 0, false, true><<<dim3(4, 8, 16), blk256, 0, stream>>>(
        Sbf, Vt, AOz, 1024, 1024, 1024, 256, M1, 262144, 262144,
        nullptr, 1.f);
    aorepack_k<<<EW, blk256, 0, stream>>>(AOz, AO);
    // 21. x += AO @ o_w^T + o_b, 512 blocks
    gemm_bf<128, 64, 0, true, false><<<dim3(16, 32, 1), blk256, 0, stream>>>(
        AO, o_wb, X, 1024, 1024, 1024, 1024, 0, 0, 0, o_b, 1.f);
    // 22-23. h = ln5(x); mid = relu(h @ c2_w^T)^2, 512 blocks
    ln_bf_k<<<4096, blk256, 0, stream>>>(X, Hbf, ln5_g, ln5_b);
    gemm_bf<128, 128, 2, false, true><<<dim3(16, 32, 1), blk256, 0, stream>>>(
        Hbf, c2_wb, Gbf, 1024, 1024, 1024, 2048, 0, 0, 0, nullptr, 1.f);
    // 24. x += mid @ c3_w^T, 512 blocks
    gemm_bf<128, 64, 0, true, false><<<dim3(16, 32, 1), blk256, 0, stream>>>(
        Gbf, c3_wb, X, 2048, 2048, 2048, 1024, 0, 0, 0, nullptr, 1.f);
    // 25. output head
    out_k<<<tgrid, tblk, 0, stream>>>(src, X, out_w, out);
}

// Round 7
// 602.772 us; speedup vs baseline: 1.3420x; 1.0328x over previous
//
#include <hip/hip_runtime.h>
#include <math.h>

// ---------------------------------------------------------------------------
// FrameTransformer — fusion round (R7). GEMM geometry = R6 (validated:
// coalesced 16row x 64B staging + swizzled conflict-free LDS + XCD swizzle).
// New: GLU fused into its GEMM (dual-B); softmax eliminated (exp in S-GEMM
// epilogue + fp32 rowsum atomics, divide in AO-GEMM epilogue); AO GEMM
// writes (B,T,F) directly; weight-prep fused into one kernel.
// ---------------------------------------------------------------------------

typedef unsigned short u16;
typedef __attribute__((ext_vector_type(4))) float floatx4;
typedef __attribute__((ext_vector_type(8))) short short8;

#define NB 4
static const long long M1 = 1024LL * 1024LL;

__device__ __forceinline__ float bf2f(u16 h) {
    union { unsigned int u; float f; } v;
    v.u = ((unsigned int)h) << 16;
    return v.f;
}
__device__ __forceinline__ u16 f2bf(float x) {
    union { float f; unsigned int u; } v;
    v.f = x;
    unsigned int r = (v.u + 0x7FFFu + ((v.u >> 16) & 1u)) >> 16;
    return (u16)r;
}

__device__ __forceinline__ void async_cp16(const u16* g, u16* lds) {
    __builtin_amdgcn_global_load_lds(
        (const __attribute__((address_space(1))) unsigned int*)g,
        (__attribute__((address_space(3))) unsigned int*)lds, 16, 0, 0);
}

__device__ __forceinline__ float block_sum(float v) {
    __shared__ float sd[4];
    #pragma unroll
    for (int off = 32; off; off >>= 1) v += __shfl_down(v, off, 64);
    int lane = threadIdx.x & 63, wid = threadIdx.x >> 6;
    __syncthreads();
    if (lane == 0) sd[wid] = v;
    __syncthreads();
    return sd[0] + sd[1] + sd[2] + sd[3];
}

// ---------------------------------------------------------------------------
// Shared GEMM geometry helpers (R6-validated).
// Staging: inst covers 16 rows x 64B; LDS 1KB blocks (rowgroup, kb),
// inside (row&15)*64 + kchunk*16. Fragment read granule: (fr*4+q)*16B.
// ---------------------------------------------------------------------------

// bf16 NT GEMM (R6 v4): C[M,N] (op)= act( scale*(A·B^T + bias) )
template<int BM, int BN, int ACT, bool ACCUM, bool OBF>
__global__ __launch_bounds__(256)
void gemm_bf(const u16* __restrict__ A, const u16* __restrict__ B,
             void* __restrict__ Cv, int K, int lda, int ldb, int ldc,
             long long sAz, long long sBz, long long sCz,
             const float* __restrict__ bias, float scale)
{
    constexpr int MI = BM / 32;
    constexpr int NJ = BN / 32;

    A += (long long)blockIdx.z * sAz;
    B += (long long)blockIdx.z * sBz;
    const long long zc = (long long)blockIdx.z * sCz;

    __shared__ u16 As[BM * 64];
    __shared__ u16 Bs[BN * 64];

    const int id = blockIdx.x + gridDim.x * blockIdx.y;
    const int bx = (id >> 3) % gridDim.x;
    const int by = (id & 7) + 8 * ((id >> 3) / gridDim.x);
    const int m0 = by * BM;
    const int n0 = bx * BN;

    const int lane = threadIdx.x & 63;
    const int w    = threadIdx.x >> 6;
    const int wm   = (w >> 1) * (BM / 2);
    const int wn   = (w & 1) * (BN / 2);
    const int srow = lane >> 2;
    const int scol = (lane & 3) * 8;

    floatx4 acc[MI][NJ];
    #pragma unroll
    for (int i = 0; i < MI; i++)
        #pragma unroll
        for (int j = 0; j < NJ; j++)
            acc[i][j] = floatx4{0.f, 0.f, 0.f, 0.f};

    for (int k0 = 0; k0 < K; k0 += 64) {
        #pragma unroll
        for (int r = 0; r < BM / 32; r++) {
            const int inst = w * (BM / 32) + r;
            const int rg = inst >> 1, kb = inst & 1;
            async_cp16(A + (long long)(m0 + rg * 16 + srow) * lda + k0 + kb * 32 + scol,
                       &As[(rg * 2 + kb) * 512]);
        }
        #pragma unroll
        for (int r = 0; r < BN / 32; r++) {
            const int inst = w * (BN / 32) + r;
            const int rg = inst >> 1, kb = inst & 1;
            async_cp16(B + (long long)(n0 + rg * 16 + srow) * ldb + k0 + kb * 32 + scol,
                       &Bs[(rg * 2 + kb) * 512]);
        }
        __syncthreads();

        #pragma unroll
        for (int s = 0; s < 2; s++) {
            short8 a[MI], b[NJ];
            const int fr = lane & 15;
            const int q  = lane >> 4;
            const int go = (fr * 4 + q) * 8;
            #pragma unroll
            for (int i = 0; i < MI; i++)
                a[i] = *(const short8*)&As[(((wm >> 4) + i) * 2 + s) * 512 + go];
            #pragma unroll
            for (int j = 0; j < NJ; j++)
                b[j] = *(const short8*)&Bs[(((wn >> 4) + j) * 2 + s) * 512 + go];
            #pragma unroll
            for (int i = 0; i < MI; i++)
                #pragma unroll
                for (int j = 0; j < NJ; j++)
                    acc[i][j] = __builtin_amdgcn_mfma_f32_16x16x32_bf16(
                        a[i], b[j], acc[i][j], 0, 0, 0);
        }
        __syncthreads();
    }

    float* Cf = (float*)Cv;
    u16*  Cb  = (u16*)Cv;
    const int cn    = n0 + wn + (lane & 15);
    const int rbase = m0 + wm + (lane >> 4) * 4;
    float bj[NJ];
    #pragma unroll
    for (int j = 0; j < NJ; j++) bj[j] = bias ? bias[cn + j * 16] : 0.f;

    #pragma unroll
    for (int i = 0; i < MI; i++) {
        #pragma unroll
        for (int r = 0; r < 4; r++) {
            const int m = rbase + i * 16 + r;
            #pragma unroll
            for (int j = 0; j < NJ; j++) {
                const int n = cn + j * 16;
                float v = (acc[i][j][r] + bj[j]) * scale;
                if (ACT == 1) v = fmaxf(v, 0.f);
                else if (ACT == 2) { v = fmaxf(v, 0.f); v = v * v; }
                const long long ci = zc + (long long)m * ldc + n;
                if (OBF)        Cb[ci] = f2bf(v);
                else if (ACCUM) Cf[ci] += v;
                else            Cf[ci] = v;
            }
        }
    }
}

// GLU-fused GEMM: X[m,n] += (A·B1^T)[m,n] * sigmoid((A·B2^T)[m,n])
// BM=128, BN=64. B1 = glu_w rows [0,1024), B2 = rows [1024,2048).
__global__ __launch_bounds__(256)
void glugemm_k(const u16* __restrict__ A, const u16* __restrict__ B1,
               const u16* __restrict__ B2, float* __restrict__ X)
{
    constexpr int BM = 128, BN = 64, MI = 4, NJ = 2;
    __shared__ u16 As[BM * 64];
    __shared__ u16 B1s[BN * 64];
    __shared__ u16 B2s[BN * 64];

    const int id = blockIdx.x + gridDim.x * blockIdx.y;
    const int bx = (id >> 3) % gridDim.x;
    const int by = (id & 7) + 8 * ((id >> 3) / gridDim.x);
    const int m0 = by * BM;
    const int n0 = bx * BN;

    const int lane = threadIdx.x & 63;
    const int w    = threadIdx.x >> 6;
    const int wm   = (w >> 1) * 64;
    const int wn   = (w & 1) * 32;
    const int srow = lane >> 2;
    const int scol = (lane & 3) * 8;

    floatx4 acc1[MI][NJ], acc2[MI][NJ];
    #pragma unroll
    for (int i = 0; i < MI; i++)
        #pragma unroll
        for (int j = 0; j < NJ; j++) {
            acc1[i][j] = floatx4{0.f, 0.f, 0.f, 0.f};
            acc2[i][j] = floatx4{0.f, 0.f, 0.f, 0.f};
        }

    for (int k0 = 0; k0 < 1024; k0 += 64) {
        #pragma unroll
        for (int r = 0; r < 4; r++) {
            const int inst = w * 4 + r;
            const int rg = inst >> 1, kb = inst & 1;
            async_cp16(A + (long long)(m0 + rg * 16 + srow) * 1024 + k0 + kb * 32 + scol,
                       &As[(rg * 2 + kb) * 512]);
        }
        #pragma unroll
        for (int r = 0; r < 2; r++) {
            const int inst = w * 2 + r;
            const int rg = inst >> 1, kb = inst & 1;
            async_cp16(B1 + (long long)(n0 + rg * 16 + srow) * 1024 + k0 + kb * 32 + scol,
                       &B1s[(rg * 2 + kb) * 512]);
            async_cp16(B2 + (long long)(n0 + rg * 16 + srow) * 1024 + k0 + kb * 32 + scol,
                       &B2s[(rg * 2 + kb) * 512]);
        }
        __syncthreads();

        #pragma unroll
        for (int s = 0; s < 2; s++) {
            short8 a[MI], b1[NJ], b2[NJ];
            const int fr = lane & 15;
            const int q  = lane >> 4;
            const int go = (fr * 4 + q) * 8;
            #pragma unroll
            for (int i = 0; i < MI; i++)
                a[i] = *(const short8*)&As[(((wm >> 4) + i) * 2 + s) * 512 + go];
            #pragma unroll
            for (int j = 0; j < NJ; j++) {
                b1[j] = *(const short8*)&B1s[(((wn >> 4) + j) * 2 + s) * 512 + go];
                b2[j] = *(const short8*)&B2s[(((wn >> 4) + j) * 2 + s) * 512 + go];
            }
            #pragma unroll
            for (int i = 0; i < MI; i++)
                #pragma unroll
                for (int j = 0; j < NJ; j++) {
                    acc1[i][j] = __builtin_amdgcn_mfma_f32_16x16x32_bf16(
                        a[i], b1[j], acc1[i][j], 0, 0, 0);
                    acc2[i][j] = __builtin_amdgcn_mfma_f32_16x16x32_bf16(
                        a[i], b2[j], acc2[i][j], 0, 0, 0);
                }
        }
        __syncthreads();
    }

    const int cn    = n0 + wn + (lane & 15);
    const int rbase = m0 + wm + (lane >> 4) * 4;
    #pragma unroll
    for (int i = 0; i < MI; i++)
        #pragma unroll
        for (int r = 0; r < 4; r++) {
            const int m = rbase + i * 16 + r;
            #pragma unroll
            for (int j = 0; j < NJ; j++) {
                const int n = cn + j * 16;
                float g = acc1[i][j][r] / (1.f + expf(-acc2[i][j][r]));
                X[(long long)m * 1024 + n] += g;
            }
        }
}

// S GEMM + exp + rowsum: S[z][m][n] = exp(scale*(A_z·B_z^T)[m,n]) (bf16),
// rowsum[z*1024+m] += partial. BM=BN=128, K=512, lda=ldb=512.
__global__ __launch_bounds__(256)
void sgemm_exp_k(const u16* __restrict__ A, const u16* __restrict__ B,
                 u16* __restrict__ S, float* __restrict__ rowsum, float scale)
{
    constexpr int BM = 128, BN = 128, MI = 4, NJ = 4;
    A += (long long)blockIdx.z * 524288;
    B += (long long)blockIdx.z * 524288;
    S += (long long)blockIdx.z * M1;
    rowsum += blockIdx.z << 10;

    __shared__ u16 As[BM * 64];
    __shared__ u16 Bs[BN * 64];

    const int id = blockIdx.x + gridDim.x * blockIdx.y;
    const int bx = (id >> 3) % gridDim.x;
    const int by = (id & 7) + 8 * ((id >> 3) / gridDim.x);
    const int m0 = by * BM;
    const int n0 = bx * BN;

    const int lane = threadIdx.x & 63;
    const int w    = threadIdx.x >> 6;
    const int wm   = (w >> 1) * 64;
    const int wn   = (w & 1) * 64;
    const int srow = lane >> 2;
    const int scol = (lane & 3) * 8;

    floatx4 acc[MI][NJ];
    #pragma unroll
    for (int i = 0; i < MI; i++)
        #pragma unroll
        for (int j = 0; j < NJ; j++)
            acc[i][j] = floatx4{0.f, 0.f, 0.f, 0.f};

    for (int k0 = 0; k0 < 512; k0 += 64) {
        #pragma unroll
        for (int r = 0; r < 4; r++) {
            const int inst = w * 4 + r;
            const int rg = inst >> 1, kb = inst & 1;
            async_cp16(A + (long long)(m0 + rg * 16 + srow) * 512 + k0 + kb * 32 + scol,
                       &As[(rg * 2 + kb) * 512]);
            async_cp16(B + (long long)(n0 + rg * 16 + srow) * 512 + k0 + kb * 32 + scol,
                       &Bs[(rg * 2 + kb) * 512]);
        }
        __syncthreads();
        #pragma unroll
        for (int s = 0; s < 2; s++) {
            short8 a[MI], b[NJ];
            const int fr = lane & 15;
            const int q  = lane >> 4;
            const int go = (fr * 4 + q) * 8;
            #pragma unroll
            for (int i = 0; i < MI; i++)
                a[i] = *(const short8*)&As[(((wm >> 4) + i) * 2 + s) * 512 + go];
            #pragma unroll
            for (int j = 0; j < NJ; j++)
                b[j] = *(const short8*)&Bs[(((wn >> 4) + j) * 2 + s) * 512 + go];
            #pragma unroll
            for (int i = 0; i < MI; i++)
                #pragma unroll
                for (int j = 0; j < NJ; j++)
                    acc[i][j] = __builtin_amdgcn_mfma_f32_16x16x32_bf16(
                        a[i], b[j], acc[i][j], 0, 0, 0);
        }
        __syncthreads();
    }

    const int cn    = n0 + wn + (lane & 15);
    const int rbase = m0 + wm + (lane >> 4) * 4;
    #pragma unroll
    for (int i = 0; i < MI; i++)
        #pragma unroll
        for (int r = 0; r < 4; r++) {
            const int m = rbase + i * 16 + r;
            float part = 0.f;
            #pragma unroll
            for (int j = 0; j < NJ; j++) {
                const int n = cn + j * 16;
                float e = expf(acc[i][j][r] * scale);
                S[(long long)m * 1024 + n] = f2bf(e);
                part += e;
            }
            // reduce across the 16 lanes holding the same row
            #pragma unroll
            for (int off = 8; off; off >>= 1) part += __shfl_xor(part, off, 64);
            if ((lane & 15) == 0) atomicAdd(&rowsum[m], part);
        }
}

// AO GEMM + rowsum divide, writes AO in (B,T,F) layout directly.
// z = b*4+band; M=1024(t), N=256(d), K=1024; out[b][t][band*256+d].
__global__ __launch_bounds__(256)
void aogemm_k(const u16* __restrict__ Sb, const u16* __restrict__ Vt,
              const float* __restrict__ rowsum, u16* __restrict__ AO)
{
    constexpr int BM = 128, BN = 64, MI = 4, NJ = 2;
    const int z = blockIdx.z;
    Sb += (long long)z * M1;
    Vt += (long long)z * 262144;
    rowsum += z << 10;
    const long long zc = (long long)(z >> 2) * M1 + (z & 3) * 256;

    __shared__ u16 As[BM * 64];
    __shared__ u16 Bs[BN * 64];

    const int id = blockIdx.x + gridDim.x * blockIdx.y;
    const int bx = (id >> 3) % gridDim.x;
    const int by = (id & 7) + 8 * ((id >> 3) / gridDim.x);
    const int m0 = by * BM;
    const int n0 = bx * BN;

    const int lane = threadIdx.x & 63;
    const int w    = threadIdx.x >> 6;
    const int wm   = (w >> 1) * 64;
    const int wn   = (w & 1) * 32;
    const int srow = lane >> 2;
    const int scol = (lane & 3) * 8;

    floatx4 acc[MI][NJ];
    #pragma unroll
    for (int i = 0; i < MI; i++)
        #pragma unroll
        for (int j = 0; j < NJ; j++)
            acc[i][j] = floatx4{0.f, 0.f, 0.f, 0.f};

    for (int k0 = 0; k0 < 1024; k0 += 64) {
        #pragma unroll
        for (int r = 0; r < 4; r++) {
            const int inst = w * 4 + r;
            const int rg = inst >> 1, kb = inst & 1;
            async_cp16(Sb + (long long)(m0 + rg * 16 + srow) * 1024 + k0 + kb * 32 + scol,
                       &As[(rg * 2 + kb) * 512]);
        }
        #pragma unroll
        for (int r = 0; r < 2; r++) {
            const int inst = w * 2 + r;
            const int rg = inst >> 1, kb = inst & 1;
            async_cp16(Vt + (long long)(n0 + rg * 16 + srow) * 1024 + k0 + kb * 32 + scol,
                       &Bs[(rg * 2 + kb) * 512]);
        }
        __syncthreads();
        #pragma unroll
        for (int s = 0; s < 2; s++) {
            short8 a[MI], b[NJ];
            const int fr = lane & 15;
            const int q  = lane >> 4;
            const int go = (fr * 4 + q) * 8;
            #pragma unroll
            for (int i = 0; i < MI; i++)
                a[i] = *(const short8*)&As[(((wm >> 4) + i) * 2 + s) * 512 + go];
            #pragma unroll
            for (int j = 0; j < NJ; j++)
                b[j] = *(const short8*)&Bs[(((wn >> 4) + j) * 2 + s) * 512 + go];
            #pragma unroll
            for (int i = 0; i < MI; i++)
                #pragma unroll
                for (int j = 0; j < NJ; j++)
                    acc[i][j] = __builtin_amdgcn_mfma_f32_16x16x32_bf16(
                        a[i], b[j], acc[i][j], 0, 0, 0);
        }
        __syncthreads();
    }

    const int cn    = n0 + wn + (lane & 15);
    const int rbase = m0 + wm + (lane >> 4) * 4;
    #pragma unroll
    for (int i = 0; i < MI; i++)
        #pragma unroll
        for (int r = 0; r < 4; r++) {
            const int m = rbase + i * 16 + r;
            const float inv = 1.f / rowsum[m];
            #pragma unroll
            for (int j = 0; j < NJ; j++) {
                const int n = cn + j * 16;
                AO[zc + (long long)m * 1024 + n] = f2bf(acc[i][j][r] * inv);
            }
        }
}

// ---------------------------------------------------------------------------
__global__ __launch_bounds__(256)
void ln_bf_k(const float* __restrict__ in, u16* __restrict__ out,
             const float* __restrict__ g, const float* __restrict__ b)
{
    long long row = blockIdx.x;
    const float4* ip = (const float4*)(in + (row << 10));
    int tid = threadIdx.x;
    float4 v = ip[tid];
    float s = v.x + v.y + v.z + v.w;
    s = block_sum(s);
    float mean = s * (1.f / 1024.f);
    float dx = v.x - mean, dy = v.y - mean, dz = v.z - mean, dw = v.w - mean;
    float s2 = dx * dx + dy * dy + dz * dz + dw * dw;
    s2 = block_sum(s2);
    float inv = rsqrtf(s2 * (1.f / 1024.f) + 1e-5f);
    float4 gg = ((const float4*)g)[tid];
    float4 bb = ((const float4*)b)[tid];
    ushort4 o;
    o.x = f2bf(dx * inv * gg.x + bb.x);
    o.y = f2bf(dy * inv * gg.y + bb.y);
    o.z = f2bf(dz * inv * gg.z + bb.z);
    o.w = f2bf(dw * inv * gg.w + bb.w);
    ((ushort4*)(out + (row << 10)))[tid] = o;
}

__global__ __launch_bounds__(256)
void inproj_k(const float* __restrict__ src, const float* __restrict__ inw,
              float* __restrict__ X)
{
    __shared__ float tile[32][33];
    int b = blockIdx.z;
    int f0 = blockIdx.y * 32, t0 = blockIdx.x * 32;
    float w0 = inw[0], w1 = inw[1];
    for (int r = threadIdx.y; r < 32; r += 8) {
        int f = f0 + r, t = t0 + threadIdx.x;
        float s0 = src[(((long long)b * 2 + 0) * 1025 + f) * 1024 + t];
        float s1 = src[(((long long)b * 2 + 1) * 1025 + f) * 1024 + t];
        tile[r][threadIdx.x] = w0 * s0 + w1 * s1;
    }
    __syncthreads();
    for (int r = threadIdx.y; r < 32; r += 8)
        X[((long long)b * 1024 + t0 + r) * 1024 + f0 + threadIdx.x] = tile[threadIdx.x][r];
}

// dconv along f (contiguous), channels=t, k=11 pad 5, transposed out[b][f][t].
__global__ __launch_bounds__(256)
void dconvF_t_k(const u16* __restrict__ in, u16* __restrict__ out,
                const float* __restrict__ w)
{
    __shared__ float itile[32][44];
    __shared__ float otile[32][33];
    int b = blockIdx.z, t0 = blockIdx.y * 32, f0 = blockIdx.x * 32;
    int tx = threadIdx.x & 31, ty = threadIdx.x >> 5;
    for (int r = ty; r < 32; r += 8)
        for (int c = tx; c < 42; c += 32) {
            int f = f0 - 5 + c;
            itile[r][c] = (f >= 0 && f < 1024)
                ? bf2f(in[((long long)(b * 1024 + t0 + r)) * 1024 + f]) : 0.f;
        }
    __syncthreads();
    for (int r = ty; r < 32; r += 8) {
        const float* wr = w + (t0 + r) * 11;
        float acc = 0.f;
        #pragma unroll
        for (int k = 0; k < 11; k++) acc += itile[r][tx + k] * wr[k];
        otile[tx][r] = acc;
    }
    __syncthreads();
    for (int r = ty; r < 32; r += 8)
        out[((long long)(b * 1024 + f0 + r)) * 1024 + t0 + tx] = f2bf(otile[r][tx]);
}

// dconv along t (strided), channels=f, k=7 pad 3, bf16 (B,T,F)->(B,T,F).
__global__ __launch_bounds__(256)
void dconvT_bf_k(const u16* __restrict__ in, u16* __restrict__ out,
                 const float* __restrict__ w)
{
    int idx = blockIdx.x * 256 + threadIdx.x;
    int f = idx & 1023;
    int bt = idx >> 10;
    int t = bt & 1023;
    int b = bt >> 10;
    const float* wr = w + f * 7;
    float acc = 0.f;
    #pragma unroll
    for (int k = 0; k < 7; k++) {
        int tt = t + k - 3;
        if (tt >= 0 && tt < 1024)
            acc += bf2f(in[(((long long)b << 10) + tt) * 1024 + f]) * wr[k];
    }
    out[idx] = f2bf(acc);
}

// V path: dconv along t on T3 v-plane + bias, transposed out Vt[b][f][t].
__global__ __launch_bounds__(256)
void vconv_t_k(const u16* __restrict__ T3, u16* __restrict__ out,
               const float* __restrict__ w, const float* __restrict__ bias)
{
    __shared__ float itile[38][32];
    __shared__ float otile[32][33];
    int b = blockIdx.z, t0 = blockIdx.y * 32, f0 = blockIdx.x * 32;
    int tx = threadIdx.x & 31, ty = threadIdx.x >> 5;
    for (int i = threadIdx.x; i < 38 * 32; i += 256) {
        int r = i >> 5, c = i & 31;
        int t = t0 - 3 + r;
        itile[r][c] = (t >= 0 && t < 1024)
            ? bf2f(T3[((long long)(b * 1024 + t)) * 3072 + 2048 + f0 + c]) : 0.f;
    }
    __syncthreads();
    for (int r = ty; r < 32; r += 8) {
        const float* wr = w + (f0 + tx) * 7;
        float acc = bias[f0 + tx];
        #pragma unroll
        for (int k = 0; k < 7; k++) acc += itile[r + k][tx] * wr[k];
        otile[tx][r] = acc;
    }
    __syncthreads();
    for (int r = ty; r < 32; r += 8)
        out[((long long)(b * 1024 + f0 + r)) * 1024 + t0 + tx] = f2bf(otile[r][tx]);
}

// Q/K path: dconv along t on T3 q,k planes + pack S-GEMM operands.
__global__ __launch_bounds__(256)
void qkpack_k(const u16* __restrict__ T3, const float* __restrict__ w,
              const float* __restrict__ bias, const u16* __restrict__ ertb,
              u16* __restrict__ Apk, u16* __restrict__ Bpk)
{
    int idx = blockIdx.x * 256 + threadIdx.x;  // 4M
    int f = idx & 1023;
    int t = (idx >> 10) & 1023;
    int b = idx >> 20;
    int band = f >> 8, d = f & 255, z = (b << 2) | band;
    const float* wr = w + f * 7;
    float bq = bias[f];
    float aq = bq, ak = bq;
    #pragma unroll
    for (int k = 0; k < 7; k++) {
        int tt = t + k - 3;
        if (tt >= 0 && tt < 1024) {
            const u16* row = T3 + ((long long)(b << 10) + tt) * 3072 + f;
            float wk = wr[k];
            aq += bf2f(row[0]) * wk;
            ak += bf2f(row[1024]) * wk;
        }
    }
    long long base = (long long)z * 524288 + t * 512 + d;
    u16 qb = f2bf(aq);
    Apk[base] = qb;
    Apk[base + 256] = ertb[t * 256 + d];
    Bpk[base] = f2bf(ak);
    Bpk[base + 256] = qb;
}

// Fused weight prep: 10 casts + er transpose + bias concat.
struct CastArgs {
    const float* s[10];
    const float* er; const float* qb; const float* kb; const float* vb;
    u16* ert; float* qkvb;
};
__global__ __launch_bounds__(256)
void castall_k(CastArgs a, u16* __restrict__ dst)
{
    const int sz[10] = {2097152, 1048576, 524288, 1048576, 1048576,
                        1048576, 1048576, 1048576, 2097152, 2097152};
    int seg = blockIdx.y;
    int tid = blockIdx.x * 256 + threadIdx.x;
    if (seg < 10) {
        int n = sz[seg];
        int base = 0;
        for (int i = 0; i < seg; i++) base += sz[i];
        int i4 = tid * 4;
        if (i4 >= n) return;
        float4 v = *(const float4*)(a.s[seg] + i4);
        ushort4 o;
        o.x = f2bf(v.x); o.y = f2bf(v.y); o.z = f2bf(v.z); o.w = f2bf(v.w);
        *(ushort4*)(dst + base + i4) = o;
    } else if (seg == 10) {
        if (tid < 262144) {
            int j = tid >> 8, d = tid & 255;
            a.ert[tid] = f2bf(a.er[d * 1024 + j]);
        }
    } else {
        if (tid < 1024) a.qkvb[tid] = a.qb[tid];
        else if (tid < 2048) a.qkvb[tid] = a.kb[tid - 1024];
        else if (tid < 3072) a.qkvb[tid] = a.vb[tid - 2048];
    }
}

__global__ __launch_bounds__(256)
void out_k(const float* __restrict__ src, const float* __restrict__ X,
           const float* __restrict__ ow, float* __restrict__ out)
{
    __shared__ float tile[32][33];
    int b = blockIdx.z;
    int f0 = blockIdx.y * 32, t0 = blockIdx.x * 32;
    for (int r = threadIdx.y; r < 32; r += 8)
        tile[r][threadIdx.x] = X[((long long)b * 1024 + t0 + r) * 1024 + f0 + threadIdx.x];
    __syncthreads();
    float w00 = ow[0], w01 = ow[1], w02 = ow[2];
    float w10 = ow[3], w11 = ow[4], w12 = ow[5];
    for (int r = threadIdx.y; r < 32; r += 8) {
        int f = f0 + r, t = t0 + threadIdx.x;
        float s0 = src[(((long long)b * 2 + 0) * 1025 + f) * 1024 + t];
        float s1 = src[(((long long)b * 2 + 1) * 1025 + f) * 1024 + t];
        float xv = tile[threadIdx.x][r];
        float v0 = fminf(fmaxf(w00 * s0 + w01 * s1 + w02 * xv, 0.f), 6.f) * (1.f / 6.f);
        float v1 = fminf(fmaxf(w10 * s0 + w11 * s1 + w12 * xv, 0.f), 6.f) * (1.f / 6.f);
        out[(((long long)b * 2 + 0) * 1025 + f) * 1024 + t] = v0;
        out[(((long long)b * 2 + 1) * 1025 + f) * 1024 + t] = v1;
        if (f == 1023) {
            out[(((long long)b * 2 + 0) * 1025 + 1024) * 1024 + t] = v0;
            out[(((long long)b * 2 + 1) * 1025 + 1024) * 1024 + t] = v1;
        }
    }
}

// ---------------------------------------------------------------------------
extern "C" void kernel_launch(void* const* d_in, const int* in_sizes, int n_in,
                              void* d_out, int out_size, void* d_ws, size_t ws_size,
                              hipStream_t stream)
{
    const float* src    = (const float*)d_in[0];
    const float* in_w   = (const float*)d_in[1];
    const float* ln1_g  = (const float*)d_in[2];
    const float* ln1_b  = (const float*)d_in[3];
    const float* glu_w  = (const float*)d_in[4];
    const float* ln2_g  = (const float*)d_in[5];
    const float* ln2_b  = (const float*)d_in[6];
    const float* c1L_dw = (const float*)d_in[7];
    const float* c1L_pw = (const float*)d_in[8];
    const float* c1R_dw = (const float*)d_in[9];
    const float* c1R_pw = (const float*)d_in[10];
    const float* ln3_g  = (const float*)d_in[11];
    const float* ln3_b  = (const float*)d_in[12];
    const float* c1M_dw = (const float*)d_in[13];
    const float* c1M_pw = (const float*)d_in[14];
    const float* ln4_g  = (const float*)d_in[15];
    const float* ln4_b  = (const float*)d_in[16];
    const float* q_w    = (const float*)d_in[17];
    const float* q_b    = (const float*)d_in[18];
    const float* qc_w   = (const float*)d_in[19];
    const float* qc_b   = (const float*)d_in[20];
    const float* k_w    = (const float*)d_in[21];
    const float* k_b    = (const float*)d_in[22];
    const float* v_w    = (const float*)d_in[23];
    const float* v_b    = (const float*)d_in[24];
    const float* o_w    = (const float*)d_in[25];
    const float* o_b    = (const float*)d_in[26];
    const float* er     = (const float*)d_in[27];
    const float* ln5_g  = (const float*)d_in[28];
    const float* ln5_b  = (const float*)d_in[29];
    const float* c2_w   = (const float*)d_in[30];
    const float* c3_w   = (const float*)d_in[31];
    const float* out_w  = (const float*)d_in[32];
    float* out = (float*)d_out;

    const size_t MB = 1ull << 20;
    if (ws_size < 162 * MB) return;
    char* wsb = (char*)d_ws;
    float* X     = (float*)(wsb + 0);         // 16 MB fp32 residual
    float* SB    = (float*)(wsb + 16 * MB);   // 16 MB fp32 hL+hR
    u16* Apk     = (u16*)(wsb + 32 * MB);     // 16 MB S-GEMM A' (z,t,512)
    u16* Bpk     = (u16*)(wsb + 48 * MB);     // 16 MB S-GEMM B'
    u16* Hbf     = (u16*)(wsb + 64 * MB);     // 8 MB ln outputs
    u16* T1bf    = (u16*)(wsb + 72 * MB);     // 8 MB dconv temps
    u16* T3      = (u16*)(wsb + 72 * MB);     // 24 MB QKV (4096x3072)
    float* rowsum= (float*)(wsb + 72 * MB);   // reuse: 64 KB (after T3 dead)
    u16* AO      = (u16*)(wsb + 80 * MB);     // 8 MB AO (B,T,F)
    u16* T2bf    = (u16*)(wsb + 96 * MB);     // 8 MB dconvF out (c1L)
    u16* Vt      = (u16*)(wsb + 96 * MB);     // reuse: 8 MB V^T (b,f,t)
    u16* Sbf     = (u16*)(wsb + 104 * MB);    // 32 MB scores (16,1024,1024)
    u16* Gbf     = (u16*)(wsb + 104 * MB);    // reuse: 16 MB ffn mid
    u16* W0      = (u16*)(wsb + 136 * MB);    // bf16 weights

    u16* glu_wb  = W0;
    u16* c1L_pwb = W0 + 2097152;
    u16* c1R_pwb = W0 + 3145728;
    u16* c1M_pwb = W0 + 3670016;
    u16* qkv_wb  = W0 + 4718592;   // q,k,v contiguous (3072 x 1024)
    u16* o_wb    = W0 + 7864320;
    u16* c2_wb   = W0 + 8912896;
    u16* c3_wb   = W0 + 11010048;
    u16* ertb    = W0 + 13107200;  // 262144
    float* qkvb  = (float*)(W0 + 13369344);  // 3072 fp32

    const dim3 blk256(256);
    const dim3 tgrid(32, 32, NB);
    const dim3 tblk(32, 8);
    const int EW = 16384;  // 4M / 256

    // --- weight prep (single kernel) ---
    CastArgs ca;
    ca.s[0] = glu_w;  ca.s[1] = c1L_pw; ca.s[2] = c1R_pw; ca.s[3] = c1M_pw;
    ca.s[4] = q_w;    ca.s[5] = k_w;    ca.s[6] = v_w;    ca.s[7] = o_w;
    ca.s[8] = c2_w;   ca.s[9] = c3_w;
    ca.er = er; ca.qb = q_b; ca.kb = k_b; ca.vb = v_b;
    ca.ert = ertb; ca.qkvb = qkvb;
    castall_k<<<dim3(2048, 12), blk256, 0, stream>>>(ca, W0);

    // 1. input projection
    inproj_k<<<tgrid, tblk, 0, stream>>>(src, in_w, X);
    // 2-4. h = ln1(x); x += glu(h @ glu_w^T)  [fused]
    ln_bf_k<<<4096, blk256, 0, stream>>>(X, Hbf, ln1_g, ln1_b);
    glugemm_k<<<dim3(16, 32, 1), blk256, 0, stream>>>(
        Hbf, glu_wb, glu_wb + 1048576, X);
    // 5. h = ln2(x)
    ln_bf_k<<<4096, blk256, 0, stream>>>(X, Hbf, ln2_g, ln2_b);
    // 6-7. hL = relu(c1L_pw · dconvF(h))
    dconvF_t_k<<<tgrid, blk256, 0, stream>>>(Hbf, T2bf, c1L_dw);
    gemm_bf<128, 64, 1, false, false><<<dim3(16, 8, NB), blk256, 0, stream>>>(
        c1L_pwb, T2bf, SB, 1024, 1024, 1024, 1024, 0, M1, M1, nullptr, 1.f);
    // 8-9. SB[:, :512] += relu(dconvT(h) @ c1R_pw^T)
    dconvT_bf_k<<<EW, blk256, 0, stream>>>(Hbf, T1bf, c1R_dw);
    gemm_bf<128, 64, 1, true, false><<<dim3(8, 32, 1), blk256, 0, stream>>>(
        T1bf, c1R_pwb, SB, 1024, 1024, 1024, 1024, 0, 0, 0, nullptr, 1.f);
    // 10-12. h = ln3(SB); x += dconvT(h) @ c1M_pw^T
    ln_bf_k<<<4096, blk256, 0, stream>>>(SB, Hbf, ln3_g, ln3_b);
    dconvT_bf_k<<<EW, blk256, 0, stream>>>(Hbf, T1bf, c1M_dw);
    gemm_bf<128, 64, 0, true, false><<<dim3(16, 32, 1), blk256, 0, stream>>>(
        T1bf, c1M_pwb, X, 1024, 1024, 1024, 1024, 0, 0, 0, nullptr, 1.f);
    // 13. h = ln4(x)
    ln_bf_k<<<4096, blk256, 0, stream>>>(X, Hbf, ln4_g, ln4_b);
    // 14. fused QKV GEMM (4096x3072x1024) -> T3 bf16
    gemm_bf<128, 128, 0, false, true><<<dim3(24, 32, 1), blk256, 0, stream>>>(
        Hbf, qkv_wb, T3, 1024, 1024, 1024, 3072, 0, 0, 0, qkvb, 1.f);
    // 15-16. qc convs: pack S operands; V transposed
    qkpack_k<<<EW, blk256, 0, stream>>>(T3, qc_w, qc_b, ertb, Apk, Bpk);
    vconv_t_k<<<tgrid, blk256, 0, stream>>>(T3, Vt, qc_w, qc_b);
    // 17. S = exp((QK^T + rel-pos)/32) + rowsum (T3 dead -> rowsum reuses it)
    hipMemsetAsync(rowsum, 0, 16 * 1024 * sizeof(float), stream);
    sgemm_exp_k<<<dim3(8, 8, 16), blk256, 0, stream>>>(
        Apk, Bpk, Sbf, rowsum, 0.03125f);
    // 18. AO = (S @ V) / rowsum, written directly to (B,T,F)
    aogemm_k<<<dim3(4, 8, 16), blk256, 0, stream>>>(Sbf, Vt, rowsum, AO);
    // 19. x += AO @ o_w^T + o_b
    gemm_bf<128, 64, 0, true, false><<<dim3(16, 32, 1), blk256, 0, stream>>>(
        AO, o_wb, X, 1024, 1024, 1024, 1024, 0, 0, 0, o_b, 1.f);
    // 20-21. h = ln5(x); mid = relu(h @ c2_w^T)^2
    ln_bf_k<<<4096, blk256, 0, stream>>>(X, Hbf, ln5_g, ln5_b);
    gemm_bf<128, 128, 2, false, true><<<dim3(16, 32, 1), blk256, 0, stream>>>(
        Hbf, c2_wb, Gbf, 1024, 1024, 1024, 2048, 0, 0, 0, nullptr, 1.f);
    // 22. x += mid @ c3_w^T
    gemm_bf<128, 64, 0, true, false><<<dim3(16, 32, 1), blk256, 0, stream>>>(
        Gbf, c3_wb, X, 2048, 2048, 2048, 1024, 0, 0, 0, nullptr, 1.f);
    // 23. output head
    out_k<<<tgrid, tblk, 0, stream>>>(src, X, out_w, out);
}

// Round 8
// 580.986 us; speedup vs baseline: 1.3923x; 1.0375x over previous
//
#include <hip/hip_runtime.h>
#include <math.h>

// ---------------------------------------------------------------------------
// FrameTransformer — R8: attention-GEMM XCD plane-affinity + bf16 residual.
// GEMM geometry = R6/R7 (validated: coalesced 16row x 64B staging + swizzled
// conflict-free LDS + m-stripe XCD swizzle for weight GEMMs).
// New: sgemm/aogemm use flattened grids with plane->XCD affinity (id%8 = XCD
// handles planes {x, x+8}; working set 4MB = one XCD L2). Residual X and SB
// are bf16 (halves traffic on inproj/glu/LN/ACCUM/out paths).
// ---------------------------------------------------------------------------

typedef unsigned short u16;
typedef __attribute__((ext_vector_type(4))) float floatx4;
typedef __attribute__((ext_vector_type(8))) short short8;

#define NB 4
static const long long M1 = 1024LL * 1024LL;

__device__ __forceinline__ float bf2f(u16 h) {
    union { unsigned int u; float f; } v;
    v.u = ((unsigned int)h) << 16;
    return v.f;
}
__device__ __forceinline__ u16 f2bf(float x) {
    union { float f; unsigned int u; } v;
    v.f = x;
    unsigned int r = (v.u + 0x7FFFu + ((v.u >> 16) & 1u)) >> 16;
    return (u16)r;
}

__device__ __forceinline__ void async_cp16(const u16* g, u16* lds) {
    __builtin_amdgcn_global_load_lds(
        (const __attribute__((address_space(1))) unsigned int*)g,
        (__attribute__((address_space(3))) unsigned int*)lds, 16, 0, 0);
}

__device__ __forceinline__ float block_sum(float v) {
    __shared__ float sd[4];
    #pragma unroll
    for (int off = 32; off; off >>= 1) v += __shfl_down(v, off, 64);
    int lane = threadIdx.x & 63, wid = threadIdx.x >> 6;
    __syncthreads();
    if (lane == 0) sd[wid] = v;
    __syncthreads();
    return sd[0] + sd[1] + sd[2] + sd[3];
}

// ---------------------------------------------------------------------------
// bf16 NT GEMM: C[M,N] (op)= act( scale*(A·B^T + bias) )
// OUT: 0 = f32 store, 1 = f32 accum, 2 = bf16 store, 3 = bf16 accum.
// ---------------------------------------------------------------------------
template<int BM, int BN, int ACT, int OUT>
__global__ __launch_bounds__(256)
void gemm_bf(const u16* __restrict__ A, const u16* __restrict__ B,
             void* __restrict__ Cv, int K, int lda, int ldb, int ldc,
             long long sAz, long long sBz, long long sCz,
             const float* __restrict__ bias, float scale)
{
    constexpr int MI = BM / 32;
    constexpr int NJ = BN / 32;

    A += (long long)blockIdx.z * sAz;
    B += (long long)blockIdx.z * sBz;
    const long long zc = (long long)blockIdx.z * sCz;

    __shared__ u16 As[BM * 64];
    __shared__ u16 Bs[BN * 64];

    const int id = blockIdx.x + gridDim.x * blockIdx.y;
    const int bx = (id >> 3) % gridDim.x;
    const int by = (id & 7) + 8 * ((id >> 3) / gridDim.x);
    const int m0 = by * BM;
    const int n0 = bx * BN;

    const int lane = threadIdx.x & 63;
    const int w    = threadIdx.x >> 6;
    const int wm   = (w >> 1) * (BM / 2);
    const int wn   = (w & 1) * (BN / 2);
    const int srow = lane >> 2;
    const int scol = (lane & 3) * 8;

    floatx4 acc[MI][NJ];
    #pragma unroll
    for (int i = 0; i < MI; i++)
        #pragma unroll
        for (int j = 0; j < NJ; j++)
            acc[i][j] = floatx4{0.f, 0.f, 0.f, 0.f};

    for (int k0 = 0; k0 < K; k0 += 64) {
        #pragma unroll
        for (int r = 0; r < BM / 32; r++) {
            const int inst = w * (BM / 32) + r;
            const int rg = inst >> 1, kb = inst & 1;
            async_cp16(A + (long long)(m0 + rg * 16 + srow) * lda + k0 + kb * 32 + scol,
                       &As[(rg * 2 + kb) * 512]);
        }
        #pragma unroll
        for (int r = 0; r < BN / 32; r++) {
            const int inst = w * (BN / 32) + r;
            const int rg = inst >> 1, kb = inst & 1;
            async_cp16(B + (long long)(n0 + rg * 16 + srow) * ldb + k0 + kb * 32 + scol,
                       &Bs[(rg * 2 + kb) * 512]);
        }
        __syncthreads();

        #pragma unroll
        for (int s = 0; s < 2; s++) {
            short8 a[MI], b[NJ];
            const int fr = lane & 15;
            const int q  = lane >> 4;
            const int go = (fr * 4 + q) * 8;
            #pragma unroll
            for (int i = 0; i < MI; i++)
                a[i] = *(const short8*)&As[(((wm >> 4) + i) * 2 + s) * 512 + go];
            #pragma unroll
            for (int j = 0; j < NJ; j++)
                b[j] = *(const short8*)&Bs[(((wn >> 4) + j) * 2 + s) * 512 + go];
            #pragma unroll
            for (int i = 0; i < MI; i++)
                #pragma unroll
                for (int j = 0; j < NJ; j++)
                    acc[i][j] = __builtin_amdgcn_mfma_f32_16x16x32_bf16(
                        a[i], b[j], acc[i][j], 0, 0, 0);
        }
        __syncthreads();
    }

    float* Cf = (float*)Cv;
    u16*  Cb  = (u16*)Cv;
    const int cn    = n0 + wn + (lane & 15);
    const int rbase = m0 + wm + (lane >> 4) * 4;
    float bj[NJ];
    #pragma unroll
    for (int j = 0; j < NJ; j++) bj[j] = bias ? bias[cn + j * 16] : 0.f;

    #pragma unroll
    for (int i = 0; i < MI; i++) {
        #pragma unroll
        for (int r = 0; r < 4; r++) {
            const int m = rbase + i * 16 + r;
            #pragma unroll
            for (int j = 0; j < NJ; j++) {
                const int n = cn + j * 16;
                float v = (acc[i][j][r] + bj[j]) * scale;
                if (ACT == 1) v = fmaxf(v, 0.f);
                else if (ACT == 2) { v = fmaxf(v, 0.f); v = v * v; }
                const long long ci = zc + (long long)m * ldc + n;
                if (OUT == 0)      Cf[ci] = v;
                else if (OUT == 1) Cf[ci] += v;
                else if (OUT == 2) Cb[ci] = f2bf(v);
                else               Cb[ci] = f2bf(bf2f(Cb[ci]) + v);
            }
        }
    }
}

// GLU-fused GEMM: X[m,n] (bf16) += (A·B1^T)[m,n] * sigmoid((A·B2^T)[m,n])
__global__ __launch_bounds__(256)
void glugemm_k(const u16* __restrict__ A, const u16* __restrict__ B1,
               const u16* __restrict__ B2, u16* __restrict__ X)
{
    constexpr int BM = 128, BN = 64, MI = 4, NJ = 2;
    __shared__ u16 As[BM * 64];
    __shared__ u16 B1s[BN * 64];
    __shared__ u16 B2s[BN * 64];

    const int id = blockIdx.x + gridDim.x * blockIdx.y;
    const int bx = (id >> 3) % gridDim.x;
    const int by = (id & 7) + 8 * ((id >> 3) / gridDim.x);
    const int m0 = by * BM;
    const int n0 = bx * BN;

    const int lane = threadIdx.x & 63;
    const int w    = threadIdx.x >> 6;
    const int wm   = (w >> 1) * 64;
    const int wn   = (w & 1) * 32;
    const int srow = lane >> 2;
    const int scol = (lane & 3) * 8;

    floatx4 acc1[MI][NJ], acc2[MI][NJ];
    #pragma unroll
    for (int i = 0; i < MI; i++)
        #pragma unroll
        for (int j = 0; j < NJ; j++) {
            acc1[i][j] = floatx4{0.f, 0.f, 0.f, 0.f};
            acc2[i][j] = floatx4{0.f, 0.f, 0.f, 0.f};
        }

    for (int k0 = 0; k0 < 1024; k0 += 64) {
        #pragma unroll
        for (int r = 0; r < 4; r++) {
            const int inst = w * 4 + r;
            const int rg = inst >> 1, kb = inst & 1;
            async_cp16(A + (long long)(m0 + rg * 16 + srow) * 1024 + k0 + kb * 32 + scol,
                       &As[(rg * 2 + kb) * 512]);
        }
        #pragma unroll
        for (int r = 0; r < 2; r++) {
            const int inst = w * 2 + r;
            const int rg = inst >> 1, kb = inst & 1;
            async_cp16(B1 + (long long)(n0 + rg * 16 + srow) * 1024 + k0 + kb * 32 + scol,
                       &B1s[(rg * 2 + kb) * 512]);
            async_cp16(B2 + (long long)(n0 + rg * 16 + srow) * 1024 + k0 + kb * 32 + scol,
                       &B2s[(rg * 2 + kb) * 512]);
        }
        __syncthreads();

        #pragma unroll
        for (int s = 0; s < 2; s++) {
            short8 a[MI], b1[NJ], b2[NJ];
            const int fr = lane & 15;
            const int q  = lane >> 4;
            const int go = (fr * 4 + q) * 8;
            #pragma unroll
            for (int i = 0; i < MI; i++)
                a[i] = *(const short8*)&As[(((wm >> 4) + i) * 2 + s) * 512 + go];
            #pragma unroll
            for (int j = 0; j < NJ; j++) {
                b1[j] = *(const short8*)&B1s[(((wn >> 4) + j) * 2 + s) * 512 + go];
                b2[j] = *(const short8*)&B2s[(((wn >> 4) + j) * 2 + s) * 512 + go];
            }
            #pragma unroll
            for (int i = 0; i < MI; i++)
                #pragma unroll
                for (int j = 0; j < NJ; j++) {
                    acc1[i][j] = __builtin_amdgcn_mfma_f32_16x16x32_bf16(
                        a[i], b1[j], acc1[i][j], 0, 0, 0);
                    acc2[i][j] = __builtin_amdgcn_mfma_f32_16x16x32_bf16(
                        a[i], b2[j], acc2[i][j], 0, 0, 0);
                }
        }
        __syncthreads();
    }

    const int cn    = n0 + wn + (lane & 15);
    const int rbase = m0 + wm + (lane >> 4) * 4;
    #pragma unroll
    for (int i = 0; i < MI; i++)
        #pragma unroll
        for (int r = 0; r < 4; r++) {
            const int m = rbase + i * 16 + r;
            #pragma unroll
            for (int j = 0; j < NJ; j++) {
                const int n = cn + j * 16;
                float g = acc1[i][j][r] / (1.f + expf(-acc2[i][j][r]));
                u16* xp = &X[(long long)m * 1024 + n];
                *xp = f2bf(bf2f(*xp) + g);
            }
        }
}

// S GEMM + exp + rowsum, plane->XCD affinity (grid 1024 1-D):
// XCD x=i&7 handles planes {x, x+8}; working set 4MB = one XCD L2.
__global__ __launch_bounds__(256)
void sgemm_exp_k(const u16* __restrict__ A, const u16* __restrict__ B,
                 u16* __restrict__ S, float* __restrict__ rowsum, float scale)
{
    constexpr int MI = 4, NJ = 4;
    const int i0 = blockIdx.x;
    const int x  = i0 & 7;
    const int j0 = i0 >> 3;            // 0..127
    const int z  = x + 8 * (j0 & 1);   // plane
    const int t  = j0 >> 1;            // 0..63
    const int bx = t & 7, by = t >> 3;

    A += (long long)z * 524288;
    B += (long long)z * 524288;
    S += (long long)z * M1;
    rowsum += z << 10;

    __shared__ u16 As[128 * 64];
    __shared__ u16 Bs[128 * 64];

    const int m0 = by * 128;
    const int n0 = bx * 128;

    const int lane = threadIdx.x & 63;
    const int w    = threadIdx.x >> 6;
    const int wm   = (w >> 1) * 64;
    const int wn   = (w & 1) * 64;
    const int srow = lane >> 2;
    const int scol = (lane & 3) * 8;

    floatx4 acc[MI][NJ];
    #pragma unroll
    for (int i = 0; i < MI; i++)
        #pragma unroll
        for (int j = 0; j < NJ; j++)
            acc[i][j] = floatx4{0.f, 0.f, 0.f, 0.f};

    for (int k0 = 0; k0 < 512; k0 += 64) {
        #pragma unroll
        for (int r = 0; r < 4; r++) {
            const int inst = w * 4 + r;
            const int rg = inst >> 1, kb = inst & 1;
            async_cp16(A + (long long)(m0 + rg * 16 + srow) * 512 + k0 + kb * 32 + scol,
                       &As[(rg * 2 + kb) * 512]);
            async_cp16(B + (long long)(n0 + rg * 16 + srow) * 512 + k0 + kb * 32 + scol,
                       &Bs[(rg * 2 + kb) * 512]);
        }
        __syncthreads();
        #pragma unroll
        for (int s = 0; s < 2; s++) {
            short8 a[MI], b[NJ];
            const int fr = lane & 15;
            const int q  = lane >> 4;
            const int go = (fr * 4 + q) * 8;
            #pragma unroll
            for (int i = 0; i < MI; i++)
                a[i] = *(const short8*)&As[(((wm >> 4) + i) * 2 + s) * 512 + go];
            #pragma unroll
            for (int j = 0; j < NJ; j++)
                b[j] = *(const short8*)&Bs[(((wn >> 4) + j) * 2 + s) * 512 + go];
            #pragma unroll
            for (int i = 0; i < MI; i++)
                #pragma unroll
                for (int j = 0; j < NJ; j++)
                    acc[i][j] = __builtin_amdgcn_mfma_f32_16x16x32_bf16(
                        a[i], b[j], acc[i][j], 0, 0, 0);
        }
        __syncthreads();
    }

    const int cn    = n0 + wn + (lane & 15);
    const int rbase = m0 + wm + (lane >> 4) * 4;
    #pragma unroll
    for (int i = 0; i < MI; i++)
        #pragma unroll
        for (int r = 0; r < 4; r++) {
            const int m = rbase + i * 16 + r;
            float part = 0.f;
            #pragma unroll
            for (int j = 0; j < NJ; j++) {
                const int n = cn + j * 16;
                float e = expf(acc[i][j][r] * scale);
                S[(long long)m * 1024 + n] = f2bf(e);
                part += e;
            }
            #pragma unroll
            for (int off = 8; off; off >>= 1) part += __shfl_xor(part, off, 64);
            if ((lane & 15) == 0) atomicAdd(&rowsum[m], part);
        }
}

// AO GEMM + rowsum divide, plane->XCD affinity (grid 512 1-D),
// writes AO in (B,T,F) layout directly.
__global__ __launch_bounds__(256)
void aogemm_k(const u16* __restrict__ Sb, const u16* __restrict__ Vt,
              const float* __restrict__ rowsum, u16* __restrict__ AO)
{
    constexpr int MI = 4, NJ = 2;
    const int i0 = blockIdx.x;
    const int x  = i0 & 7;
    const int j0 = i0 >> 3;            // 0..63
    const int z  = x + 8 * (j0 & 1);
    const int t  = j0 >> 1;            // 0..31
    const int bx = t & 3, by = t >> 2;

    Sb += (long long)z * M1;
    Vt += (long long)z * 262144;
    rowsum += z << 10;
    const long long zc = (long long)(z >> 2) * M1 + (z & 3) * 256;

    __shared__ u16 As[128 * 64];
    __shared__ u16 Bs[64 * 64];

    const int m0 = by * 128;
    const int n0 = bx * 64;

    const int lane = threadIdx.x & 63;
    const int w    = threadIdx.x >> 6;
    const int wm   = (w >> 1) * 64;
    const int wn   = (w & 1) * 32;
    const int srow = lane >> 2;
    const int scol = (lane & 3) * 8;

    floatx4 acc[MI][NJ];
    #pragma unroll
    for (int i = 0; i < MI; i++)
        #pragma unroll
        for (int j = 0; j < NJ; j++)
            acc[i][j] = floatx4{0.f, 0.f, 0.f, 0.f};

    for (int k0 = 0; k0 < 1024; k0 += 64) {
        #pragma unroll
        for (int r = 0; r < 4; r++) {
            const int inst = w * 4 + r;
            const int rg = inst >> 1, kb = inst & 1;
            async_cp16(Sb + (long long)(m0 + rg * 16 + srow) * 1024 + k0 + kb * 32 + scol,
                       &As[(rg * 2 + kb) * 512]);
        }
        #pragma unroll
        for (int r = 0; r < 2; r++) {
            const int inst = w * 2 + r;
            const int rg = inst >> 1, kb = inst & 1;
            async_cp16(Vt + (long long)(n0 + rg * 16 + srow) * 1024 + k0 + kb * 32 + scol,
                       &Bs[(rg * 2 + kb) * 512]);
        }
        __syncthreads();
        #pragma unroll
        for (int s = 0; s < 2; s++) {
            short8 a[MI], b[NJ];
            const int fr = lane & 15;
            const int q  = lane >> 4;
            const int go = (fr * 4 + q) * 8;
            #pragma unroll
            for (int i = 0; i < MI; i++)
                a[i] = *(const short8*)&As[(((wm >> 4) + i) * 2 + s) * 512 + go];
            #pragma unroll
            for (int j = 0; j < NJ; j++)
                b[j] = *(const short8*)&Bs[(((wn >> 4) + j) * 2 + s) * 512 + go];
            #pragma unroll
            for (int i = 0; i < MI; i++)
                #pragma unroll
                for (int j = 0; j < NJ; j++)
                    acc[i][j] = __builtin_amdgcn_mfma_f32_16x16x32_bf16(
                        a[i], b[j], acc[i][j], 0, 0, 0);
        }
        __syncthreads();
    }

    const int cn    = n0 + wn + (lane & 15);
    const int rbase = m0 + wm + (lane >> 4) * 4;
    #pragma unroll
    for (int i = 0; i < MI; i++)
        #pragma unroll
        for (int r = 0; r < 4; r++) {
            const int m = rbase + i * 16 + r;
            const float inv = 1.f / rowsum[m];
            #pragma unroll
            for (int j = 0; j < NJ; j++) {
                const int n = cn + j * 16;
                AO[zc + (long long)m * 1024 + n] = f2bf(acc[i][j][r] * inv);
            }
        }
}

// ---------------------------------------------------------------------------
// LayerNorm: bf16 in -> bf16 out. One block per row.
__global__ __launch_bounds__(256)
void ln_bf_k(const u16* __restrict__ in, u16* __restrict__ out,
             const float* __restrict__ g, const float* __restrict__ b)
{
    long long row = blockIdx.x;
    int tid = threadIdx.x;
    ushort4 u = ((const ushort4*)(in + (row << 10)))[tid];
    float x0 = bf2f(u.x), x1 = bf2f(u.y), x2 = bf2f(u.z), x3 = bf2f(u.w);
    float s = x0 + x1 + x2 + x3;
    s = block_sum(s);
    float mean = s * (1.f / 1024.f);
    float dx = x0 - mean, dy = x1 - mean, dz = x2 - mean, dw = x3 - mean;
    float s2 = dx * dx + dy * dy + dz * dz + dw * dw;
    s2 = block_sum(s2);
    float inv = rsqrtf(s2 * (1.f / 1024.f) + 1e-5f);
    float4 gg = ((const float4*)g)[tid];
    float4 bb = ((const float4*)b)[tid];
    ushort4 o;
    o.x = f2bf(dx * inv * gg.x + bb.x);
    o.y = f2bf(dy * inv * gg.y + bb.y);
    o.z = f2bf(dz * inv * gg.z + bb.z);
    o.w = f2bf(dw * inv * gg.w + bb.w);
    ((ushort4*)(out + (row << 10)))[tid] = o;
}

// Input projection -> bf16 X
__global__ __launch_bounds__(256)
void inproj_k(const float* __restrict__ src, const float* __restrict__ inw,
              u16* __restrict__ X)
{
    __shared__ float tile[32][33];
    int b = blockIdx.z;
    int f0 = blockIdx.y * 32, t0 = blockIdx.x * 32;
    float w0 = inw[0], w1 = inw[1];
    for (int r = threadIdx.y; r < 32; r += 8) {
        int f = f0 + r, t = t0 + threadIdx.x;
        float s0 = src[(((long long)b * 2 + 0) * 1025 + f) * 1024 + t];
        float s1 = src[(((long long)b * 2 + 1) * 1025 + f) * 1024 + t];
        tile[r][threadIdx.x] = w0 * s0 + w1 * s1;
    }
    __syncthreads();
    for (int r = threadIdx.y; r < 32; r += 8)
        X[((long long)b * 1024 + t0 + r) * 1024 + f0 + threadIdx.x] = f2bf(tile[threadIdx.x][r]);
}

// dconv along f (contiguous), channels=t, k=11 pad 5, transposed out[b][f][t].
__global__ __launch_bounds__(256)
void dconvF_t_k(const u16* __restrict__ in, u16* __restrict__ out,
                const float* __restrict__ w)
{
    __shared__ float itile[32][44];
    __shared__ float otile[32][33];
    int b = blockIdx.z, t0 = blockIdx.y * 32, f0 = blockIdx.x * 32;
    int tx = threadIdx.x & 31, ty = threadIdx.x >> 5;
    for (int r = ty; r < 32; r += 8)
        for (int c = tx; c < 42; c += 32) {
            int f = f0 - 5 + c;
            itile[r][c] = (f >= 0 && f < 1024)
                ? bf2f(in[((long long)(b * 1024 + t0 + r)) * 1024 + f]) : 0.f;
        }
    __syncthreads();
    for (int r = ty; r < 32; r += 8) {
        const float* wr = w + (t0 + r) * 11;
        float acc = 0.f;
        #pragma unroll
        for (int k = 0; k < 11; k++) acc += itile[r][tx + k] * wr[k];
        otile[tx][r] = acc;
    }
    __syncthreads();
    for (int r = ty; r < 32; r += 8)
        out[((long long)(b * 1024 + f0 + r)) * 1024 + t0 + tx] = f2bf(otile[r][tx]);
}

// dconv along t (strided), channels=f, k=7 pad 3, bf16 (B,T,F)->(B,T,F).
__global__ __launch_bounds__(256)
void dconvT_bf_k(const u16* __restrict__ in, u16* __restrict__ out,
                 const float* __restrict__ w)
{
    int idx = blockIdx.x * 256 + threadIdx.x;
    int f = idx & 1023;
    int bt = idx >> 10;
    int t = bt & 1023;
    int b = bt >> 10;
    const float* wr = w + f * 7;
    float acc = 0.f;
    #pragma unroll
    for (int k = 0; k < 7; k++) {
        int tt = t + k - 3;
        if (tt >= 0 && tt < 1024)
            acc += bf2f(in[(((long long)b << 10) + tt) * 1024 + f]) * wr[k];
    }
    out[idx] = f2bf(acc);
}

// V path: dconv along t on T3 v-plane + bias, transposed out Vt[b][f][t].
__global__ __launch_bounds__(256)
void vconv_t_k(const u16* __restrict__ T3, u16* __restrict__ out,
               const float* __restrict__ w, const float* __restrict__ bias)
{
    __shared__ float itile[38][32];
    __shared__ float otile[32][33];
    int b = blockIdx.z, t0 = blockIdx.y * 32, f0 = blockIdx.x * 32;
    int tx = threadIdx.x & 31, ty = threadIdx.x >> 5;
    for (int i = threadIdx.x; i < 38 * 32; i += 256) {
        int r = i >> 5, c = i & 31;
        int t = t0 - 3 + r;
        itile[r][c] = (t >= 0 && t < 1024)
            ? bf2f(T3[((long long)(b * 1024 + t)) * 3072 + 2048 + f0 + c]) : 0.f;
    }
    __syncthreads();
    for (int r = ty; r < 32; r += 8) {
        const float* wr = w + (f0 + tx) * 7;
        float acc = bias[f0 + tx];
        #pragma unroll
        for (int k = 0; k < 7; k++) acc += itile[r + k][tx] * wr[k];
        otile[tx][r] = acc;
    }
    __syncthreads();
    for (int r = ty; r < 32; r += 8)
        out[((long long)(b * 1024 + f0 + r)) * 1024 + t0 + tx] = f2bf(otile[r][tx]);
}

// Q/K path: dconv along t on T3 q,k planes + pack S-GEMM operands.
__global__ __launch_bounds__(256)
void qkpack_k(const u16* __restrict__ T3, const float* __restrict__ w,
              const float* __restrict__ bias, const u16* __restrict__ ertb,
              u16* __restrict__ Apk, u16* __restrict__ Bpk)
{
    int idx = blockIdx.x * 256 + threadIdx.x;  // 4M
    int f = idx & 1023;
    int t = (idx >> 10) & 1023;
    int b = idx >> 20;
    int band = f >> 8, d = f & 255, z = (b << 2) | band;
    const float* wr = w + f * 7;
    float bq = bias[f];
    float aq = bq, ak = bq;
    #pragma unroll
    for (int k = 0; k < 7; k++) {
        int tt = t + k - 3;
        if (tt >= 0 && tt < 1024) {
            const u16* row = T3 + ((long long)(b << 10) + tt) * 3072 + f;
            float wk = wr[k];
            aq += bf2f(row[0]) * wk;
            ak += bf2f(row[1024]) * wk;
        }
    }
    long long base = (long long)z * 524288 + t * 512 + d;
    u16 qb = f2bf(aq);
    Apk[base] = qb;
    Apk[base + 256] = ertb[t * 256 + d];
    Bpk[base] = f2bf(ak);
    Bpk[base + 256] = qb;
}

// Fused weight prep: 10 casts + er transpose + bias concat.
struct CastArgs {
    const float* s[10];
    const float* er; const float* qb; const float* kb; const float* vb;
    u16* ert; float* qkvb;
};
__global__ __launch_bounds__(256)
void castall_k(CastArgs a, u16* __restrict__ dst)
{
    const int sz[10] = {2097152, 1048576, 524288, 1048576, 1048576,
                        1048576, 1048576, 1048576, 2097152, 2097152};
    int seg = blockIdx.y;
    int tid = blockIdx.x * 256 + threadIdx.x;
    if (seg < 10) {
        int n = sz[seg];
        int base = 0;
        for (int i = 0; i < seg; i++) base += sz[i];
        int i4 = tid * 4;
        if (i4 >= n) return;
        float4 v = *(const float4*)(a.s[seg] + i4);
        ushort4 o;
        o.x = f2bf(v.x); o.y = f2bf(v.y); o.z = f2bf(v.z); o.w = f2bf(v.w);
        *(ushort4*)(dst + base + i4) = o;
    } else if (seg == 10) {
        if (tid < 262144) {
            int j = tid >> 8, d = tid & 255;
            a.ert[tid] = f2bf(a.er[d * 1024 + j]);
        }
    } else {
        if (tid < 1024) a.qkvb[tid] = a.qb[tid];
        else if (tid < 2048) a.qkvb[tid] = a.kb[tid - 1024];
        else if (tid < 3072) a.qkvb[tid] = a.vb[tid - 2048];
    }
}

// Output head: reads bf16 X.
__global__ __launch_bounds__(256)
void out_k(const float* __restrict__ src, const u16* __restrict__ X,
           const float* __restrict__ ow, float* __restrict__ out)
{
    __shared__ float tile[32][33];
    int b = blockIdx.z;
    int f0 = blockIdx.y * 32, t0 = blockIdx.x * 32;
    for (int r = threadIdx.y; r < 32; r += 8)
        tile[r][threadIdx.x] = bf2f(X[((long long)b * 1024 + t0 + r) * 1024 + f0 + threadIdx.x]);
    __syncthreads();
    float w00 = ow[0], w01 = ow[1], w02 = ow[2];
    float w10 = ow[3], w11 = ow[4], w12 = ow[5];
    for (int r = threadIdx.y; r < 32; r += 8) {
        int f = f0 + r, t = t0 + threadIdx.x;
        float s0 = src[(((long long)b * 2 + 0) * 1025 + f) * 1024 + t];
        float s1 = src[(((long long)b * 2 + 1) * 1025 + f) * 1024 + t];
        float xv = tile[threadIdx.x][r];
        float v0 = fminf(fmaxf(w00 * s0 + w01 * s1 + w02 * xv, 0.f), 6.f) * (1.f / 6.f);
        float v1 = fminf(fmaxf(w10 * s0 + w11 * s1 + w12 * xv, 0.f), 6.f) * (1.f / 6.f);
        out[(((long long)b * 2 + 0) * 1025 + f) * 1024 + t] = v0;
        out[(((long long)b * 2 + 1) * 1025 + f) * 1024 + t] = v1;
        if (f == 1023) {
            out[(((long long)b * 2 + 0) * 1025 + 1024) * 1024 + t] = v0;
            out[(((long long)b * 2 + 1) * 1025 + 1024) * 1024 + t] = v1;
        }
    }
}

// ---------------------------------------------------------------------------
extern "C" void kernel_launch(void* const* d_in, const int* in_sizes, int n_in,
                              void* d_out, int out_size, void* d_ws, size_t ws_size,
                              hipStream_t stream)
{
    const float* src    = (const float*)d_in[0];
    const float* in_w   = (const float*)d_in[1];
    const float* ln1_g  = (const float*)d_in[2];
    const float* ln1_b  = (const float*)d_in[3];
    const float* glu_w  = (const float*)d_in[4];
    const float* ln2_g  = (const float*)d_in[5];
    const float* ln2_b  = (const float*)d_in[6];
    const float* c1L_dw = (const float*)d_in[7];
    const float* c1L_pw = (const float*)d_in[8];
    const float* c1R_dw = (const float*)d_in[9];
    const float* c1R_pw = (const float*)d_in[10];
    const float* ln3_g  = (const float*)d_in[11];
    const float* ln3_b  = (const float*)d_in[12];
    const float* c1M_dw = (const float*)d_in[13];
    const float* c1M_pw = (const float*)d_in[14];
    const float* ln4_g  = (const float*)d_in[15];
    const float* ln4_b  = (const float*)d_in[16];
    const float* q_w    = (const float*)d_in[17];
    const float* q_b    = (const float*)d_in[18];
    const float* qc_w   = (const float*)d_in[19];
    const float* qc_b   = (const float*)d_in[20];
    const float* k_w    = (const float*)d_in[21];
    const float* k_b    = (const float*)d_in[22];
    const float* v_w    = (const float*)d_in[23];
    const float* v_b    = (const float*)d_in[24];
    const float* o_w    = (const float*)d_in[25];
    const float* o_b    = (const float*)d_in[26];
    const float* er     = (const float*)d_in[27];
    const float* ln5_g  = (const float*)d_in[28];
    const float* ln5_b  = (const float*)d_in[29];
    const float* c2_w   = (const float*)d_in[30];
    const float* c3_w   = (const float*)d_in[31];
    const float* out_w  = (const float*)d_in[32];
    float* out = (float*)d_out;

    const size_t MB = 1ull << 20;
    if (ws_size < 162 * MB) return;
    char* wsb = (char*)d_ws;
    u16* X       = (u16*)(wsb + 0);           // 8 MB bf16 residual
    u16* SB      = (u16*)(wsb + 8 * MB);      // 8 MB bf16 hL+hR
    u16* Apk     = (u16*)(wsb + 32 * MB);     // 16 MB S-GEMM A' (z,t,512)
    u16* Bpk     = (u16*)(wsb + 48 * MB);     // 16 MB S-GEMM B'
    u16* Hbf     = (u16*)(wsb + 64 * MB);     // 8 MB ln outputs
    u16* T1bf    = (u16*)(wsb + 72 * MB);     // 8 MB dconv temps
    u16* T3      = (u16*)(wsb + 72 * MB);     // 24 MB QKV (4096x3072)
    float* rowsum= (float*)(wsb + 72 * MB);   // reuse: 64 KB (after T3 dead)
    u16* AO      = (u16*)(wsb + 80 * MB);     // 8 MB AO (B,T,F)
    u16* T2bf    = (u16*)(wsb + 96 * MB);     // 8 MB dconvF out (c1L)
    u16* Vt      = (u16*)(wsb + 96 * MB);     // reuse: 8 MB V^T (b,f,t)
    u16* Sbf     = (u16*)(wsb + 104 * MB);    // 32 MB scores (16,1024,1024)
    u16* Gbf     = (u16*)(wsb + 104 * MB);    // reuse: 16 MB ffn mid
    u16* W0      = (u16*)(wsb + 136 * MB);    // bf16 weights

    u16* glu_wb  = W0;
    u16* c1L_pwb = W0 + 2097152;
    u16* c1R_pwb = W0 + 3145728;
    u16* c1M_pwb = W0 + 3670016;
    u16* qkv_wb  = W0 + 4718592;   // q,k,v contiguous (3072 x 1024)
    u16* o_wb    = W0 + 7864320;
    u16* c2_wb   = W0 + 8912896;
    u16* c3_wb   = W0 + 11010048;
    u16* ertb    = W0 + 13107200;  // 262144
    float* qkvb  = (float*)(W0 + 13369344);  // 3072 fp32

    const dim3 blk256(256);
    const dim3 tgrid(32, 32, NB);
    const dim3 tblk(32, 8);
    const int EW = 16384;  // 4M / 256

    // --- weight prep (single kernel) ---
    CastArgs ca;
    ca.s[0] = glu_w;  ca.s[1] = c1L_pw; ca.s[2] = c1R_pw; ca.s[3] = c1M_pw;
    ca.s[4] = q_w;    ca.s[5] = k_w;    ca.s[6] = v_w;    ca.s[7] = o_w;
    ca.s[8] = c2_w;   ca.s[9] = c3_w;
    ca.er = er; ca.qb = q_b; ca.kb = k_b; ca.vb = v_b;
    ca.ert = ertb; ca.qkvb = qkvb;
    castall_k<<<dim3(2048, 12), blk256, 0, stream>>>(ca, W0);

    // 1. input projection (bf16 X)
    inproj_k<<<tgrid, tblk, 0, stream>>>(src, in_w, X);
    // 2-4. h = ln1(x); x += glu(h @ glu_w^T)  [fused]
    ln_bf_k<<<4096, blk256, 0, stream>>>(X, Hbf, ln1_g, ln1_b);
    glugemm_k<<<dim3(16, 32, 1), blk256, 0, stream>>>(
        Hbf, glu_wb, glu_wb + 1048576, X);
    // 5. h = ln2(x)
    ln_bf_k<<<4096, blk256, 0, stream>>>(X, Hbf, ln2_g, ln2_b);
    // 6-7. hL = relu(c1L_pw · dconvF(h)) -> bf16 SB
    dconvF_t_k<<<tgrid, blk256, 0, stream>>>(Hbf, T2bf, c1L_dw);
    gemm_bf<128, 64, 1, 2><<<dim3(16, 8, NB), blk256, 0, stream>>>(
        c1L_pwb, T2bf, SB, 1024, 1024, 1024, 1024, 0, M1, M1, nullptr, 1.f);
    // 8-9. SB[:, :512] += relu(dconvT(h) @ c1R_pw^T)  (bf16 accum)
    dconvT_bf_k<<<EW, blk256, 0, stream>>>(Hbf, T1bf, c1R_dw);
    gemm_bf<128, 64, 1, 3><<<dim3(8, 32, 1), blk256, 0, stream>>>(
        T1bf, c1R_pwb, SB, 1024, 1024, 1024, 1024, 0, 0, 0, nullptr, 1.f);
    // 10-12. h = ln3(SB); x += dconvT(h) @ c1M_pw^T  (bf16 accum)
    ln_bf_k<<<4096, blk256, 0, stream>>>(SB, Hbf, ln3_g, ln3_b);
    dconvT_bf_k<<<EW, blk256, 0, stream>>>(Hbf, T1bf, c1M_dw);
    gemm_bf<128, 64, 0, 3><<<dim3(16, 32, 1), blk256, 0, stream>>>(
        T1bf, c1M_pwb, X, 1024, 1024, 1024, 1024, 0, 0, 0, nullptr, 1.f);
    // 13. h = ln4(x)
    ln_bf_k<<<4096, blk256, 0, stream>>>(X, Hbf, ln4_g, ln4_b);
    // 14. fused QKV GEMM (4096x3072x1024) -> T3 bf16
    gemm_bf<128, 128, 0, 2><<<dim3(24, 32, 1), blk256, 0, stream>>>(
        Hbf, qkv_wb, T3, 1024, 1024, 1024, 3072, 0, 0, 0, qkvb, 1.f);
    // 15-16. qc convs: pack S operands; V transposed
    qkpack_k<<<EW, blk256, 0, stream>>>(T3, qc_w, qc_b, ertb, Apk, Bpk);
    vconv_t_k<<<tgrid, blk256, 0, stream>>>(T3, Vt, qc_w, qc_b);
    // 17. S = exp((QK^T + rel-pos)/32) + rowsum; plane->XCD affinity
    hipMemsetAsync(rowsum, 0, 16 * 1024 * sizeof(float), stream);
    sgemm_exp_k<<<1024, blk256, 0, stream>>>(Apk, Bpk, Sbf, rowsum, 0.03125f);
    // 18. AO = (S @ V) / rowsum; plane->XCD affinity; (B,T,F) layout
    aogemm_k<<<512, blk256, 0, stream>>>(Sbf, Vt, rowsum, AO);
    // 19. x += AO @ o_w^T + o_b  (bf16 accum)
    gemm_bf<128, 64, 0, 3><<<dim3(16, 32, 1), blk256, 0, stream>>>(
        AO, o_wb, X, 1024, 1024, 1024, 1024, 0, 0, 0, o_b, 1.f);
    // 20-21. h = ln5(x); mid = relu(h @ c2_w^T)^2
    ln_bf_k<<<4096, blk256, 0, stream>>>(X, Hbf, ln5_g, ln5_b);
    gemm_bf<128, 128, 2, 2><<<dim3(16, 32, 1), blk256, 0, stream>>>(
        Hbf, c2_wb, Gbf, 1024, 1024, 1024, 2048, 0, 0, 0, nullptr, 1.f);
    // 22. x += mid @ c3_w^T  (bf16 accum)
    gemm_bf<128, 64, 0, 3><<<dim3(16, 32, 1), blk256, 0, stream>>>(
        Gbf, c3_wb, X, 2048, 2048, 2048, 1024, 0, 0, 0, nullptr, 1.f);
    // 23. output head
    out_k<<<tgrid, tblk, 0, stream>>>(src, X, out_w, out);
}